// Round 11
// baseline (522.635 us; speedup 1.0000x reference)
//
#include <hip/hip_runtime.h>
#include <hip/hip_fp16.h>
#include <cstdint>
#include <cstddef>

// Problem constants (fixed by the reference)
#define N_A   50000
#define N_B   50000
#define E_AB  320000
#define E_AA  320000
#define IN_DIM 128
#define HID    128
#define ED     64

using bf16x8 = __attribute__((ext_vector_type(8))) short;
using f32x4  = __attribute__((ext_vector_type(4))) float;
typedef unsigned short ushort_t;
typedef unsigned int   uint_t;

__device__ inline ushort_t bf16r(float f) {   // f32 -> bf16 bits, RNE
    uint_t u = __float_as_uint(f);
    u = (u + 0x7FFF + ((u >> 16) & 1)) >> 16;
    return (ushort_t)u;
}
__device__ inline float bf2f(ushort_t h) {
    return __uint_as_float(((uint_t)h) << 16);
}
__device__ inline ushort_t f16r(float f) { return __half_as_ushort(__float2half_rn(f)); }
__device__ inline float f16f(ushort_t u) { return __half2float(__ushort_as_half(u)); }
__device__ inline uint_t packh2(float a, float b) {
    return (uint_t)f16r(a) | ((uint_t)f16r(b) << 16);
}

__device__ inline void online_merge(float& m, float& l, float om, float ol) {
    const float nm = fmaxf(m, om);
    l = l * __expf(m - nm) + ol * __expf(om - nm);
    m = nm;
}

// ---------------------------------------------------------------------------
// Pre-pack all weights into bf16 hi/lo MFMA B-fragments + permuted w_e.
// ---------------------------------------------------------------------------
__global__ __launch_bounds__(64) void prep_w_all(
    const float* __restrict__ Wh, const float* __restrict__ W1,
    const float* __restrict__ W2, const float* __restrict__ FT,
    const float* __restrict__ we,
    ushort_t* __restrict__ BhWh, ushort_t* __restrict__ BlWh,
    ushort_t* __restrict__ BhW1, ushort_t* __restrict__ BlW1,
    ushort_t* __restrict__ BhW2, ushort_t* __restrict__ BlW2,
    ushort_t* __restrict__ BhFT, ushort_t* __restrict__ BlFT,
    float* __restrict__ wep)
{
    const int f = blockIdx.x;
    const int lane = threadIdx.x;
    if (f == 112) {
#pragma unroll
        for (int q = 0; q < 2; ++q) {
            const int idx = lane + q * 64;
            const int l15 = idx >> 3, ct = idx & 7;
            wep[idx] = we[ct * 16 + l15];
        }
        return;
    }
    const float* W; ushort_t *oh, *ol; int KT, fl;
    if (f < 16)      { W = Wh; oh = BhWh; ol = BlWh; KT = 2; fl = f; }
    else if (f < 48) { W = W1; oh = BhW1; ol = BlW1; KT = 4; fl = f - 16; }
    else if (f < 80) { W = W2; oh = BhW2; ol = BlW2; KT = 4; fl = f - 48; }
    else             { W = FT; oh = BhFT; ol = BlFT; KT = 4; fl = f - 80; }
    const int ct = fl / KT, kt = fl % KT;
    const int col = ct * 16 + (lane & 15);
    const int kb  = kt * 32 + (lane >> 4) * 8;
#pragma unroll
    for (int j = 0; j < 8; ++j) {
        const float v = W[(kb + j) * 128 + col];
        const ushort_t h = bf16r(v);
        oh[(size_t)(fl * 64 + lane) * 8 + j] = h;
        ol[(size_t)(fl * 64 + lane) * 8 + j] = bf16r(v - bf2f(h));
    }
}

// ---------------------------------------------------------------------------
// proj_dual: P1 = x_a@W1 + (bh+bn), P2 = x_a@W2, f16 interleaved; emits xa16.
// ---------------------------------------------------------------------------
__global__ __launch_bounds__(256) void proj_dual_mfma(
    const float* __restrict__ X,
    const ushort_t* __restrict__ B1h, const ushort_t* __restrict__ B1l,
    const ushort_t* __restrict__ B2h, const ushort_t* __restrict__ B2l,
    const float* __restrict__ bh, const float* __restrict__ bn,
    ushort_t* __restrict__ P1, ushort_t* __restrict__ P2,
    ushort_t* __restrict__ X16, int N)
{
    const int lane = threadIdx.x & 63;
    const int l15 = lane & 15, lg = lane >> 4;
    const int r0 = blockIdx.x * 64 + (threadIdx.x >> 6) * 16;
    const int arow = (r0 + l15 < N) ? (r0 + l15) : (N - 1);

    bf16x8 ahi[4], alo[4];
#pragma unroll
    for (int kt = 0; kt < 4; ++kt) {
        float v[8];
        *(float4*)(v + 0) = *(const float4*)&X[(size_t)arow * 128 + kt * 32 + lg * 8];
        *(float4*)(v + 4) = *(const float4*)&X[(size_t)arow * 128 + kt * 32 + lg * 8 + 4];
        uint4 xu;
        xu.x = packh2(v[0], v[1]); xu.y = packh2(v[2], v[3]);
        xu.z = packh2(v[4], v[5]); xu.w = packh2(v[6], v[7]);
        *(uint4*)&X16[(size_t)arow * 128 + kt * 32 + lg * 8] = xu;
#pragma unroll
        for (int j = 0; j < 8; ++j) {
            const ushort_t h = bf16r(v[j]);
            ahi[kt][j] = (short)h;
            alo[kt][j] = (short)bf16r(v[j] - bf2f(h));
        }
    }

    f32x4 acc1[8], acc2[8];
#pragma unroll
    for (int ct = 0; ct < 8; ++ct) {
        const float b = bh[ct * 16 + l15] + bn[ct * 16 + l15];
        acc1[ct] = (f32x4){b, b, b, b};
        acc2[ct] = (f32x4){0.f, 0.f, 0.f, 0.f};
    }

#pragma unroll
    for (int ct = 0; ct < 8; ++ct) {
#pragma unroll
        for (int kt = 0; kt < 4; ++kt) {
            const size_t fo = (size_t)((ct * 4 + kt) * 64 + lane) * 8;
            const bf16x8 b1h = *(const bf16x8*)&B1h[fo];
            const bf16x8 b1l = *(const bf16x8*)&B1l[fo];
            const bf16x8 b2h = *(const bf16x8*)&B2h[fo];
            const bf16x8 b2l = *(const bf16x8*)&B2l[fo];
            acc1[ct] = __builtin_amdgcn_mfma_f32_16x16x32_bf16(ahi[kt], b1h, acc1[ct], 0, 0, 0);
            acc1[ct] = __builtin_amdgcn_mfma_f32_16x16x32_bf16(alo[kt], b1h, acc1[ct], 0, 0, 0);
            acc1[ct] = __builtin_amdgcn_mfma_f32_16x16x32_bf16(ahi[kt], b1l, acc1[ct], 0, 0, 0);
            acc2[ct] = __builtin_amdgcn_mfma_f32_16x16x32_bf16(ahi[kt], b2h, acc2[ct], 0, 0, 0);
            acc2[ct] = __builtin_amdgcn_mfma_f32_16x16x32_bf16(alo[kt], b2h, acc2[ct], 0, 0, 0);
            acc2[ct] = __builtin_amdgcn_mfma_f32_16x16x32_bf16(ahi[kt], b2l, acc2[ct], 0, 0, 0);
        }
    }
#pragma unroll
    for (int i = 0; i < 4; ++i) {
        const int row = r0 + lg * 4 + i;
        if (row < N) {
            uint4 u1, u2;
            u1.x = packh2(acc1[0][i], acc1[1][i]); u1.y = packh2(acc1[2][i], acc1[3][i]);
            u1.z = packh2(acc1[4][i], acc1[5][i]); u1.w = packh2(acc1[6][i], acc1[7][i]);
            u2.x = packh2(acc2[0][i], acc2[1][i]); u2.y = packh2(acc2[2][i], acc2[3][i]);
            u2.z = packh2(acc2[4][i], acc2[5][i]); u2.w = packh2(acc2[6][i], acc2[7][i]);
            *(uint4*)&P1[(size_t)row * 128 + l15 * 8] = u1;
            *(uint4*)&P2[(size_t)row * 128 + l15 * 8] = u2;
        }
    }
}

// proj_single: P = x_b@W2 (no bias), f16 interleaved; emits xb16.
__global__ __launch_bounds__(256) void proj_single_mfma(
    const float* __restrict__ X,
    const ushort_t* __restrict__ Bh, const ushort_t* __restrict__ Bl,
    ushort_t* __restrict__ P, ushort_t* __restrict__ X16, int N)
{
    const int lane = threadIdx.x & 63;
    const int l15 = lane & 15, lg = lane >> 4;
    const int r0 = blockIdx.x * 64 + (threadIdx.x >> 6) * 16;
    const int arow = (r0 + l15 < N) ? (r0 + l15) : (N - 1);

    bf16x8 ahi[4], alo[4];
#pragma unroll
    for (int kt = 0; kt < 4; ++kt) {
        float v[8];
        *(float4*)(v + 0) = *(const float4*)&X[(size_t)arow * 128 + kt * 32 + lg * 8];
        *(float4*)(v + 4) = *(const float4*)&X[(size_t)arow * 128 + kt * 32 + lg * 8 + 4];
        uint4 xu;
        xu.x = packh2(v[0], v[1]); xu.y = packh2(v[2], v[3]);
        xu.z = packh2(v[4], v[5]); xu.w = packh2(v[6], v[7]);
        *(uint4*)&X16[(size_t)arow * 128 + kt * 32 + lg * 8] = xu;
#pragma unroll
        for (int j = 0; j < 8; ++j) {
            const ushort_t h = bf16r(v[j]);
            ahi[kt][j] = (short)h;
            alo[kt][j] = (short)bf16r(v[j] - bf2f(h));
        }
    }

    f32x4 acc[8];
#pragma unroll
    for (int ct = 0; ct < 8; ++ct) acc[ct] = (f32x4){0.f, 0.f, 0.f, 0.f};

#pragma unroll
    for (int ct = 0; ct < 8; ++ct) {
#pragma unroll
        for (int kt = 0; kt < 4; ++kt) {
            const size_t fo = (size_t)((ct * 4 + kt) * 64 + lane) * 8;
            const bf16x8 bhf = *(const bf16x8*)&Bh[fo];
            const bf16x8 blf = *(const bf16x8*)&Bl[fo];
            acc[ct] = __builtin_amdgcn_mfma_f32_16x16x32_bf16(ahi[kt], bhf, acc[ct], 0, 0, 0);
            acc[ct] = __builtin_amdgcn_mfma_f32_16x16x32_bf16(alo[kt], bhf, acc[ct], 0, 0, 0);
            acc[ct] = __builtin_amdgcn_mfma_f32_16x16x32_bf16(ahi[kt], blf, acc[ct], 0, 0, 0);
        }
    }
#pragma unroll
    for (int i = 0; i < 4; ++i) {
        const int row = r0 + lg * 4 + i;
        if (row < N) {
            uint4 u;
            u.x = packh2(acc[0][i], acc[1][i]); u.y = packh2(acc[2][i], acc[3][i]);
            u.z = packh2(acc[4][i], acc[5][i]); u.w = packh2(acc[6][i], acc[7][i]);
            *(uint4*)&P[(size_t)row * 128 + l15 * 8] = u;
        }
    }
}

// ---------------------------------------------------------------------------
// Merged edge-score kernel, 512-thread blocks, decoupled:
//  - only Bh staged in LDS (16.4 KB = 1024 uint4!); Bl read from global (L2)
//  - single (staging) barrier; NO trailing barrier: per-wave pm/pl
//  - CSR count+rank atomics issued AFTER compute
//  grid 5000: blocks [0,2500) -> AB (128 edges), [2500,5000) -> AA.
// ---------------------------------------------------------------------------
__global__ __launch_bounds__(512, 8) void edge_score_k(
    const float* __restrict__ ea_ab, const float* __restrict__ ea_aa,
    const int*   __restrict__ ei_ab, const int*   __restrict__ ei_aa,
    const ushort_t* __restrict__ P1h,
    const ushort_t* __restrict__ P2ah, const ushort_t* __restrict__ P2bh,
    const ushort_t* __restrict__ Bhi,  const ushort_t* __restrict__ Blo,
    const float* __restrict__ wep,
    float* __restrict__ scAB, float* __restrict__ scAA,
    int* __restrict__ cntA, int* __restrict__ cntB,
    int* __restrict__ rkAab, int* __restrict__ rkBab, int* __restrict__ rkAaa,
    float* __restrict__ pm, float* __restrict__ pl)
{
    const int t    = threadIdx.x;
    const int lane = t & 63;
    const int l15  = lane & 15;
    const int lg   = lane >> 4;
    const int wv   = t >> 6;                        // 0..7
    const int type = (blockIdx.x >= 2500);
    const int bb   = type ? (blockIdx.x - 2500) : blockIdx.x;
    const int eb   = bb * 128;
    const int gw   = blockIdx.x * 8 + wv;           // per-wave partial slot

    const float* __restrict__ ea  = type ? ea_aa : ea_ab;
    const int*   __restrict__ ei  = type ? ei_aa : ei_ab;
    const ushort_t* __restrict__ P2h = type ? P2ah : P2bh;
    float* __restrict__ score = type ? scAA : scAB;

    __shared__ ushort_t sBh[8192];   // 16 KB = 1024 uint4 (Bh only)
    {
        const uint4* gh = (const uint4*)Bhi;   // 1024 uint4 total
        uint4* sh = (uint4*)sBh;
        sh[t]       = gh[t];          // t in [0,512)
        sh[t + 512] = gh[t + 512];    // second half — BOTH halves staged
    }

    const int e0 = eb + wv * 16;   // this wave's 16 edges

    // hoisted indices (int4) + P gathers (fly under A-conversion + MFMA)
    const int4 sv = *(const int4*)&ei[e0 + lg * 4];
    const int4 dv = *(const int4*)&ei[(size_t)E_AB + e0 + lg * 4];
    const int sidx[4] = {sv.x, sv.y, sv.z, sv.w};
    const int didx[4] = {dv.x, dv.y, dv.z, dv.w};
    uint4 p1u[4], p2u[4];
#pragma unroll
    for (int i = 0; i < 4; ++i) {
        p1u[i] = *(const uint4*)&P1h[(size_t)sidx[i] * 128 + l15 * 8];
        p2u[i] = *(const uint4*)&P2h[(size_t)didx[i] * 128 + l15 * 8];
    }

    float w8[8];
    *(float4*)(w8 + 0) = *(const float4*)&wep[l15 * 8];
    *(float4*)(w8 + 4) = *(const float4*)&wep[l15 * 8 + 4];

    // A fragment: row = l15 (edge e0+l15), k = kt*32 + lg*8 + j
    const float* arow = &ea[(size_t)(e0 + l15) * 64 + lg * 8];
    float af[16];
    *(float4*)(af + 0)  = *(const float4*)(arow + 0);
    *(float4*)(af + 4)  = *(const float4*)(arow + 4);
    *(float4*)(af + 8)  = *(const float4*)(arow + 32);
    *(float4*)(af + 12) = *(const float4*)(arow + 36);

    bf16x8 ahi0, alo0, ahi1, alo1;
#pragma unroll
    for (int j = 0; j < 8; ++j) {
        const ushort_t h0 = bf16r(af[j]);
        ahi0[j] = (short)h0;
        alo0[j] = (short)bf16r(af[j] - bf2f(h0));
        const ushort_t h1 = bf16r(af[8 + j]);
        ahi1[j] = (short)h1;
        alo1[j] = (short)bf16r(af[8 + j] - bf2f(h1));
    }

    __syncthreads();   // staging complete (only barrier in the kernel)

    f32x4 acc[8];
#pragma unroll
    for (int ct = 0; ct < 8; ++ct) acc[ct] = (f32x4){0.f, 0.f, 0.f, 0.f};

#pragma unroll
    for (int ct = 0; ct < 8; ++ct) {
        const bf16x8 bh0 = *(const bf16x8*)&sBh[(ct * 2 + 0) * 512 + lane * 8];
        const bf16x8 bh1 = *(const bf16x8*)&sBh[(ct * 2 + 1) * 512 + lane * 8];
        const bf16x8 bl0 = *(const bf16x8*)&Blo[(size_t)(ct * 2 + 0) * 512 + lane * 8];
        const bf16x8 bl1 = *(const bf16x8*)&Blo[(size_t)(ct * 2 + 1) * 512 + lane * 8];
        acc[ct] = __builtin_amdgcn_mfma_f32_16x16x32_bf16(ahi0, bh0, acc[ct], 0, 0, 0);
        acc[ct] = __builtin_amdgcn_mfma_f32_16x16x32_bf16(alo0, bh0, acc[ct], 0, 0, 0);
        acc[ct] = __builtin_amdgcn_mfma_f32_16x16x32_bf16(ahi0, bl0, acc[ct], 0, 0, 0);
        acc[ct] = __builtin_amdgcn_mfma_f32_16x16x32_bf16(ahi1, bh1, acc[ct], 0, 0, 0);
        acc[ct] = __builtin_amdgcn_mfma_f32_16x16x32_bf16(alo1, bh1, acc[ct], 0, 0, 0);
        acc[ct] = __builtin_amdgcn_mfma_f32_16x16x32_bf16(ahi1, bl1, acc[ct], 0, 0, 0);
    }

    float part[4];
#pragma unroll
    for (int i = 0; i < 4; ++i) {
        const __half2* h1 = (const __half2*)&p1u[i];
        const __half2* h2 = (const __half2*)&p2u[i];
        float p = 0.f;
#pragma unroll
        for (int q = 0; q < 4; ++q) {
            const float2 pf = __half22float2(__hadd2(h1[q], h2[q]));
            p = fmaf(fmaxf(acc[2 * q][i] + pf.x, 0.f), w8[2 * q], p);
            p = fmaf(fmaxf(acc[2 * q + 1][i] + pf.y, 0.f), w8[2 * q + 1], p);
        }
        part[i] = p;
    }
#pragma unroll
    for (int m = 8; m >= 1; m >>= 1) {
#pragma unroll
        for (int i = 0; i < 4; ++i) part[i] += __shfl_xor(part[i], m, 64);
    }
    if (l15 == 0) {
#pragma unroll
        for (int i = 0; i < 4; ++i) score[e0 + lg * 4 + i] = part[i];
    }

    // per-wave softmax partial (no cross-wave reduce, no barrier)
    float mw = fmaxf(fmaxf(part[0], part[1]), fmaxf(part[2], part[3]));
    float lw = __expf(part[0] - mw) + __expf(part[1] - mw)
             + __expf(part[2] - mw) + __expf(part[3] - mw);
#pragma unroll
    for (int off = 16; off <= 32; off <<= 1) {
        const float om = __shfl_xor(mw, off, 64);
        const float ol = __shfl_xor(lw, off, 64);
        online_merge(mw, lw, om, ol);
    }
    if (lane == 0) { pm[gw] = mw; pl[gw] = lw; }

    // CSR count + rank LAST (latency overlaps other blocks' compute)
    if (t < 128) {
        const int e = eb + t;
        const int s = ei[e];
        const int r = atomicAdd(&cntA[s], 1);
        if (type) rkAaa[e] = r; else rkAab[e] = r;
    } else if (t < 256 && !type) {
        const int e = eb + (t - 128);
        const int d = ei[(size_t)E_AB + e];
        rkBab[e] = atomicAdd(&cntB[d], 1);
    }
}

// ---------------------------------------------------------------------------
// Final softmax reduction over wave partials; grid 2 (type per block)
// ---------------------------------------------------------------------------
__global__ __launch_bounds__(1024) void softmax_final_kernel(
    const float* __restrict__ pm, const float* __restrict__ pl,
    float* __restrict__ ML, int nPart)
{
    const int type = blockIdx.x;
    const float* mi = pm + type * nPart;
    const float* li = pl + type * nPart;
    float m = -1e30f, l = 0.f;
    for (int i = threadIdx.x; i < nPart; i += 1024) online_merge(m, l, mi[i], li[i]);
#pragma unroll
    for (int off = 1; off < 64; off <<= 1) {
        const float om = __shfl_xor(m, off, 64);
        const float ol = __shfl_xor(l, off, 64);
        online_merge(m, l, om, ol);
    }
    __shared__ float smm[16], sll[16];
    const int w = threadIdx.x >> 6, lane = threadIdx.x & 63;
    if (lane == 0) { smm[w] = m; sll[w] = l; }
    __syncthreads();
    if (threadIdx.x == 0) {
        float M = smm[0], L = sll[0];
        for (int i = 1; i < 16; ++i) online_merge(M, L, smm[i], sll[i]);
        ML[type * 2]     = M;
        ML[type * 2 + 1] = L;
    }
}

// ---------------------------------------------------------------------------
// CSR scan
// ---------------------------------------------------------------------------
__global__ __launch_bounds__(1024) void csr_scan_kernel(
    const int* __restrict__ cntA, int* __restrict__ offA,
    const int* __restrict__ cntB, int* __restrict__ offB, int N)
{
    const int* cnt = (blockIdx.x == 0) ? cntA : cntB;
    int* off = (blockIdx.x == 0) ? offA : offB;

    __shared__ int warpsum[16];
    const int t = threadIdx.x, lane = t & 63, w = t >> 6;
    int carry = 0;

    for (int base = 0; base < N; base += 1024) {
        const int i = base + t;
        const int v = (i < N) ? cnt[i] : 0;
        int x = v;
#pragma unroll
        for (int d = 1; d < 64; d <<= 1) {
            const int y = __shfl_up(x, d, 64);
            if (lane >= d) x += y;
        }
        if (lane == 63) warpsum[w] = x;
        __syncthreads();
        if (w == 0 && lane < 16) {
            int s = warpsum[lane];
#pragma unroll
            for (int d = 1; d < 16; d <<= 1) {
                const int y = __shfl_up(s, d, 64);
                if (lane >= d) s += y;
            }
            warpsum[lane] = s;
        }
        __syncthreads();
        const int excl = (x - v) + ((w > 0) ? warpsum[w - 1] : 0) + carry;
        if (i < N) off[i] = excl;
        carry += warpsum[15];
        __syncthreads();
    }
    if (t == 0) off[N] = carry;
}

// Atomic-free fill with fused softmax normalization (positions clamped for
// rocprof-replay atomic-inflation safety).
__global__ __launch_bounds__(256) void csr_fill_kernel(
    const int* __restrict__ ei_ab, const int* __restrict__ ei_aa,
    float* __restrict__ scAB, float* __restrict__ scAA,
    const float* __restrict__ ML,
    const int* __restrict__ offA, const int* __restrict__ offB,
    const int* __restrict__ rkAab, const int* __restrict__ rkBab,
    const int* __restrict__ rkAaa,
    int2* __restrict__ idxA, int2* __restrict__ idxB)
{
    const int i = blockIdx.x * 256 + threadIdx.x;
    const float Mab = ML[0], rLab = 1.0f / ML[1];
    const float Maa = ML[2], rLaa = 1.0f / ML[3];
    if (i < E_AB) {
        const float a = __expf(scAB[i] - Mab) * rLab;
        scAB[i] = a;
        const int s = ei_ab[i], d = ei_ab[E_AB + i];
        const int ab = __float_as_int(a);
        int pA = offA[s] + rkAab[i]; if (pA > 2 * E_AB - 1) pA = 2 * E_AB - 1;
        int pB = offB[d] + rkBab[i]; if (pB > E_AB - 1) pB = E_AB - 1;
        idxA[pA] = make_int2(d | (1 << 20), ab);
        idxB[pB] = make_int2(s, ab);
    }
    if (i < E_AA) {
        const float a = __expf(scAA[i] - Maa) * rLaa;
        scAA[i] = a;
        const int s = ei_aa[i];
        const int daa = ei_aa[E_AA + i];
        int pA = offA[s] + rkAaa[i]; if (pA > 2 * E_AB - 1) pA = 2 * E_AB - 1;
        idxA[pA] = make_int2(daa, __float_as_int(a));
    }
}

// ---------------------------------------------------------------------------
// Fused gather + final. Phase 1: quarter-wave per row, 4-wide entry unroll.
// Phase 2: final MFMA (T <- T + T@FT + fb) on the same 16 rows (L2-hot).
// ---------------------------------------------------------------------------
__global__ __launch_bounds__(256) void gather_final(
    const int*  __restrict__ off, const int2* __restrict__ idx,
    const ushort_t* __restrict__ xa16, const ushort_t* __restrict__ xb16,
    const float* __restrict__ xself,
    const ushort_t* __restrict__ Bh, const ushort_t* __restrict__ Bl,
    const float* __restrict__ fb,
    float* __restrict__ T, int N)
{
    const int lane = threadIdx.x & 63;
    const int l15  = lane & 15, lg = lane >> 4;
    const int wv   = threadIdx.x >> 6;
    const int r0   = blockIdx.x * 64 + wv * 16;

    for (int s = 0; s < 4; ++s) {
        const int row = r0 + s * 4 + lg;
        if (row < N) {
            const int beg = off[row], end = off[row + 1];
            float a8[8];
            *(float4*)(a8 + 0) = *(const float4*)&xself[(size_t)row * 128 + l15 * 8];
            *(float4*)(a8 + 4) = *(const float4*)&xself[(size_t)row * 128 + l15 * 8 + 4];
            int e = beg;
            for (; e + 3 < end; e += 4) {
                int2 q[4];
#pragma unroll
                for (int k = 0; k < 4; ++k) q[k] = idx[e + k];
                uint4 f[4];
#pragma unroll
                for (int k = 0; k < 4; ++k) {
                    const ushort_t* sp = (q[k].x & (1 << 20)) ? xb16 : xa16;
                    f[k] = *(const uint4*)&sp[(size_t)(q[k].x & 0xFFFFF) * 128 + l15 * 8];
                }
#pragma unroll
                for (int k = 0; k < 4; ++k) {
                    const float al = __int_as_float(q[k].y);
                    const __half2* hp = (const __half2*)&f[k];
#pragma unroll
                    for (int j = 0; j < 4; ++j) {
                        const float2 vf = __half22float2(hp[j]);
                        a8[2 * j]     = fmaf(-al, vf.x, a8[2 * j]);
                        a8[2 * j + 1] = fmaf(-al, vf.y, a8[2 * j + 1]);
                    }
                }
            }
            for (; e < end; ++e) {
                const int2 q0 = idx[e];
                const float al = __int_as_float(q0.y);
                const ushort_t* sp = (q0.x & (1 << 20)) ? xb16 : xa16;
                const uint4 f0 = *(const uint4*)&sp[(size_t)(q0.x & 0xFFFFF) * 128 + l15 * 8];
                const __half2* hp = (const __half2*)&f0;
#pragma unroll
                for (int j = 0; j < 4; ++j) {
                    const float2 vf = __half22float2(hp[j]);
                    a8[2 * j]     = fmaf(-al, vf.x, a8[2 * j]);
                    a8[2 * j + 1] = fmaf(-al, vf.y, a8[2 * j + 1]);
                }
            }
            *(float4*)&T[(size_t)row * 128 + l15 * 8]     = *(float4*)(a8 + 0);
            *(float4*)&T[(size_t)row * 128 + l15 * 8 + 4] = *(float4*)(a8 + 4);
        }
    }
    __syncthreads();

    const int arow = (r0 + l15 < N) ? (r0 + l15) : (N - 1);
    bf16x8 ahi[4], alo[4];
#pragma unroll
    for (int kt = 0; kt < 4; ++kt) {
        float v[8];
        *(float4*)(v + 0) = *(const float4*)&T[(size_t)arow * 128 + kt * 32 + lg * 8];
        *(float4*)(v + 4) = *(const float4*)&T[(size_t)arow * 128 + kt * 32 + lg * 8 + 4];
#pragma unroll
        for (int j = 0; j < 8; ++j) {
            const ushort_t h = bf16r(v[j]);
            ahi[kt][j] = (short)h;
            alo[kt][j] = (short)bf16r(v[j] - bf2f(h));
        }
    }

    f32x4 acc[8];
#pragma unroll
    for (int ct = 0; ct < 8; ++ct) {
        const float b = fb[ct * 16 + l15];
#pragma unroll
        for (int i = 0; i < 4; ++i) {
            const int row = r0 + lg * 4 + i;
            const int rr = (row < N) ? row : (N - 1);
            acc[ct][i] = T[(size_t)rr * 128 + ct * 16 + l15] + b;
        }
    }

#pragma unroll
    for (int ct = 0; ct < 8; ++ct) {
#pragma unroll
        for (int kt = 0; kt < 4; ++kt) {
            const size_t fo = (size_t)((ct * 4 + kt) * 64 + lane) * 8;
            const bf16x8 bhf = *(const bf16x8*)&Bh[fo];
            const bf16x8 blf = *(const bf16x8*)&Bl[fo];
            acc[ct] = __builtin_amdgcn_mfma_f32_16x16x32_bf16(ahi[kt], bhf, acc[ct], 0, 0, 0);
            acc[ct] = __builtin_amdgcn_mfma_f32_16x16x32_bf16(alo[kt], bhf, acc[ct], 0, 0, 0);
            acc[ct] = __builtin_amdgcn_mfma_f32_16x16x32_bf16(ahi[kt], blf, acc[ct], 0, 0, 0);
        }
    }
#pragma unroll
    for (int ct = 0; ct < 8; ++ct) {
#pragma unroll
        for (int i = 0; i < 4; ++i) {
            const int row = r0 + lg * 4 + i;
            if (row < N) T[(size_t)row * 128 + ct * 16 + l15] = acc[ct][i];
        }
    }
}

// ---------------------------------------------------------------------------
extern "C" void kernel_launch(void* const* d_in, const int* in_sizes, int n_in,
                              void* d_out, int out_size, void* d_ws, size_t ws_size,
                              hipStream_t stream)
{
    const float* x_a   = (const float*)d_in[0];
    const float* x_b   = (const float*)d_in[1];
    const int*   ei_ab = (const int*)d_in[2];
    const float* ea_ab = (const float*)d_in[3];
    const int*   ei_aa = (const int*)d_in[4];
    const float* ea_aa = (const float*)d_in[5];
    const float* Wh_w  = (const float*)d_in[6];
    const float* Wh_b  = (const float*)d_in[7];
    const float* Wn_w  = (const float*)d_in[8];
    const float* Wn_b  = (const float*)d_in[9];
    const float* w_e   = (const float*)d_in[10];
    const float* ft_w  = (const float*)d_in[11];
    const float* ft_b  = (const float*)d_in[12];

    float* out = (float*)d_out;
    float* ws  = (float*)d_ws;

    // ws layout (float offsets; all regions disjoint)
    ushort_t* P1h  = (ushort_t*)(ws);              // 6.4M ushorts
    ushort_t* P2ah = (ushort_t*)(ws + 3200000);
    ushort_t* P2bh = (ushort_t*)(ws + 6400000);
    ushort_t* xa16 = (ushort_t*)(ws + 9600000);
    ushort_t* xb16 = (ushort_t*)(ws + 12800000);
    int* rkAab = (int*)(ws + 16000000);
    int* rkBab = (int*)(ws + 16320000);
    int* rkAaa = (int*)(ws + 16640000);
    int* cntA  = (int*)(ws + 16960000);            // cntA+cntB contiguous
    int* cntB  = (int*)(ws + 17010000);
    int* offA  = (int*)(ws + 17060000);            // 50001
    int* offB  = (int*)(ws + 17110004);            // 50001
    float* pm  = ws + 17160008;                    // 40000 (20000 per type)
    float* pl  = ws + 17200008;                    // 40000
    float* ML  = ws + 17240008;                    // 4
    float* wep = ws + 17240016;                    // 128
    ushort_t* FR = (ushort_t*)(ws + 17240208);     // 114688 ushorts
    ushort_t* BhWh = FR;
    ushort_t* BlWh = FR + 8192;
    ushort_t* BhW1 = FR + 16384;
    ushort_t* BlW1 = FR + 32768;
    ushort_t* BhW2 = FR + 49152;
    ushort_t* BlW2 = FR + 65536;
    ushort_t* BhFT = FR + 81920;
    ushort_t* BlFT = FR + 98304;                   // ends ws+17297552
    int2* idxA = (int2*)(ws + 17300000);           // 640000 entries
    int2* idxB = (int2*)(ws + 18580000);           // 320000 entries -> 19220000

    // d_out layout: out_a[6.4M] out_b[6.4M] alpha_ab[320K] alpha_aa[320K]
    float* TA   = out;
    float* TB   = out + 6400000;
    float* alAB = out + 12800000;   // raw scores, then normalized in csr_fill
    float* alAA = out + 13120000;

    // 0) zero CSR counters; pack weights
    hipMemsetAsync(cntA, 0, 100000 * sizeof(int), stream);
    prep_w_all<<<113, 64, 0, stream>>>(Wh_w, Wn_w, Wn_w + 128 * 128, ft_w, w_e,
                                       BhWh, BlWh, BhW1, BlW1, BhW2, BlW2, BhFT, BlFT, wep);

    // 1) node projections (f16 tables, interleaved layout) + f16 x copies
    proj_dual_mfma<<<(N_A + 63) / 64, 256, 0, stream>>>(x_a, BhW1, BlW1, BhW2, BlW2,
                                                        Wh_b, Wn_b, P1h, P2ah, xa16, N_A);
    proj_single_mfma<<<(N_B + 63) / 64, 256, 0, stream>>>(x_b, BhW2, BlW2, P2bh, xb16, N_B);

    // 2) merged edge scores, decoupled 512-thread blocks
    edge_score_k<<<5000, 512, 0, stream>>>(ea_ab, ea_aa, ei_ab, ei_aa,
                                           P1h, P2ah, P2bh, BhWh, BlWh, wep,
                                           alAB, alAA, cntA, cntB,
                                           rkAab, rkBab, rkAaa, pm, pl);

    // 3) softmax final reduction (both types; 20000 wave partials each)
    softmax_final_kernel<<<2, 1024, 0, stream>>>(pm, pl, ML, 20000);

    // 4) CSR scan + atomic-free fill (fused normalization)
    csr_scan_kernel<<<2, 1024, 0, stream>>>(cntA, offA, cntB, offB, N_A);
    csr_fill_kernel<<<(E_AB + 255) / 256, 256, 0, stream>>>(ei_ab, ei_aa, alAB, alAA, ML,
                                                            offA, offB, rkAab, rkBab, rkAaa,
                                                            idxA, idxB);

    // 5) fused gather + final transform
    gather_final<<<(N_A + 63) / 64, 256, 0, stream>>>(offA, idxA, xa16, xb16, x_a,
                                                      BhFT, BlFT, ft_b, TA, N_A);
    gather_final<<<(N_B + 63) / 64, 256, 0, stream>>>(offB, idxB, xa16, xb16, x_b,
                                                      BhFT, BlFT, ft_b, TB, N_B);

    (void)in_sizes; (void)n_in; (void)out_size; (void)ws_size;
}

// Round 12
// 375.778 us; speedup vs baseline: 1.3908x; 1.3908x over previous
//
#include <hip/hip_runtime.h>
#include <hip/hip_fp16.h>
#include <cstdint>
#include <cstddef>

// Problem constants (fixed by the reference)
#define N_A   50000
#define N_B   50000
#define E_AB  320000
#define E_AA  320000
#define IN_DIM 128
#define HID    128
#define ED     64

using bf16x8 = __attribute__((ext_vector_type(8))) short;
using f32x4  = __attribute__((ext_vector_type(4))) float;
typedef unsigned short ushort_t;
typedef unsigned int   uint_t;

__device__ inline ushort_t bf16r(float f) {   // f32 -> bf16 bits, RNE
    uint_t u = __float_as_uint(f);
    u = (u + 0x7FFF + ((u >> 16) & 1)) >> 16;
    return (ushort_t)u;
}
__device__ inline float bf2f(ushort_t h) {
    return __uint_as_float(((uint_t)h) << 16);
}
__device__ inline ushort_t f16r(float f) { return __half_as_ushort(__float2half_rn(f)); }
__device__ inline float f16f(ushort_t u) { return __half2float(__ushort_as_half(u)); }
__device__ inline uint_t packh2(float a, float b) {
    return (uint_t)f16r(a) | ((uint_t)f16r(b) << 16);
}

__device__ inline void online_merge(float& m, float& l, float om, float ol) {
    const float nm = fmaxf(m, om);
    l = l * __expf(m - nm) + ol * __expf(om - nm);
    m = nm;
}

// ---------------------------------------------------------------------------
// Pre-pack all weights into bf16 hi/lo MFMA B-fragments + permuted w_e.
// ---------------------------------------------------------------------------
__global__ __launch_bounds__(64) void prep_w_all(
    const float* __restrict__ Wh, const float* __restrict__ W1,
    const float* __restrict__ W2, const float* __restrict__ FT,
    const float* __restrict__ we,
    ushort_t* __restrict__ BhWh, ushort_t* __restrict__ BlWh,
    ushort_t* __restrict__ BhW1, ushort_t* __restrict__ BlW1,
    ushort_t* __restrict__ BhW2, ushort_t* __restrict__ BlW2,
    ushort_t* __restrict__ BhFT, ushort_t* __restrict__ BlFT,
    float* __restrict__ wep)
{
    const int f = blockIdx.x;
    const int lane = threadIdx.x;
    if (f == 112) {
#pragma unroll
        for (int q = 0; q < 2; ++q) {
            const int idx = lane + q * 64;
            const int l15 = idx >> 3, ct = idx & 7;
            wep[idx] = we[ct * 16 + l15];
        }
        return;
    }
    const float* W; ushort_t *oh, *ol; int KT, fl;
    if (f < 16)      { W = Wh; oh = BhWh; ol = BlWh; KT = 2; fl = f; }
    else if (f < 48) { W = W1; oh = BhW1; ol = BlW1; KT = 4; fl = f - 16; }
    else if (f < 80) { W = W2; oh = BhW2; ol = BlW2; KT = 4; fl = f - 48; }
    else             { W = FT; oh = BhFT; ol = BlFT; KT = 4; fl = f - 80; }
    const int ct = fl / KT, kt = fl % KT;
    const int col = ct * 16 + (lane & 15);
    const int kb  = kt * 32 + (lane >> 4) * 8;
#pragma unroll
    for (int j = 0; j < 8; ++j) {
        const float v = W[(kb + j) * 128 + col];
        const ushort_t h = bf16r(v);
        oh[(size_t)(fl * 64 + lane) * 8 + j] = h;
        ol[(size_t)(fl * 64 + lane) * 8 + j] = bf16r(v - bf2f(h));
    }
}

// ---------------------------------------------------------------------------
// proj_dual: P1 = x_a@W1 + (bh+bn), P2 = x_a@W2, f16 interleaved; emits xa16.
// ---------------------------------------------------------------------------
__global__ __launch_bounds__(256) void proj_dual_mfma(
    const float* __restrict__ X,
    const ushort_t* __restrict__ B1h, const ushort_t* __restrict__ B1l,
    const ushort_t* __restrict__ B2h, const ushort_t* __restrict__ B2l,
    const float* __restrict__ bh, const float* __restrict__ bn,
    ushort_t* __restrict__ P1, ushort_t* __restrict__ P2,
    ushort_t* __restrict__ X16, int N)
{
    const int lane = threadIdx.x & 63;
    const int l15 = lane & 15, lg = lane >> 4;
    const int r0 = blockIdx.x * 64 + (threadIdx.x >> 6) * 16;
    const int arow = (r0 + l15 < N) ? (r0 + l15) : (N - 1);

    bf16x8 ahi[4], alo[4];
#pragma unroll
    for (int kt = 0; kt < 4; ++kt) {
        float v[8];
        *(float4*)(v + 0) = *(const float4*)&X[(size_t)arow * 128 + kt * 32 + lg * 8];
        *(float4*)(v + 4) = *(const float4*)&X[(size_t)arow * 128 + kt * 32 + lg * 8 + 4];
        uint4 xu;
        xu.x = packh2(v[0], v[1]); xu.y = packh2(v[2], v[3]);
        xu.z = packh2(v[4], v[5]); xu.w = packh2(v[6], v[7]);
        *(uint4*)&X16[(size_t)arow * 128 + kt * 32 + lg * 8] = xu;
#pragma unroll
        for (int j = 0; j < 8; ++j) {
            const ushort_t h = bf16r(v[j]);
            ahi[kt][j] = (short)h;
            alo[kt][j] = (short)bf16r(v[j] - bf2f(h));
        }
    }

    f32x4 acc1[8], acc2[8];
#pragma unroll
    for (int ct = 0; ct < 8; ++ct) {
        const float b = bh[ct * 16 + l15] + bn[ct * 16 + l15];
        acc1[ct] = (f32x4){b, b, b, b};
        acc2[ct] = (f32x4){0.f, 0.f, 0.f, 0.f};
    }

#pragma unroll
    for (int ct = 0; ct < 8; ++ct) {
#pragma unroll
        for (int kt = 0; kt < 4; ++kt) {
            const size_t fo = (size_t)((ct * 4 + kt) * 64 + lane) * 8;
            const bf16x8 b1h = *(const bf16x8*)&B1h[fo];
            const bf16x8 b1l = *(const bf16x8*)&B1l[fo];
            const bf16x8 b2h = *(const bf16x8*)&B2h[fo];
            const bf16x8 b2l = *(const bf16x8*)&B2l[fo];
            acc1[ct] = __builtin_amdgcn_mfma_f32_16x16x32_bf16(ahi[kt], b1h, acc1[ct], 0, 0, 0);
            acc1[ct] = __builtin_amdgcn_mfma_f32_16x16x32_bf16(alo[kt], b1h, acc1[ct], 0, 0, 0);
            acc1[ct] = __builtin_amdgcn_mfma_f32_16x16x32_bf16(ahi[kt], b1l, acc1[ct], 0, 0, 0);
            acc2[ct] = __builtin_amdgcn_mfma_f32_16x16x32_bf16(ahi[kt], b2h, acc2[ct], 0, 0, 0);
            acc2[ct] = __builtin_amdgcn_mfma_f32_16x16x32_bf16(alo[kt], b2h, acc2[ct], 0, 0, 0);
            acc2[ct] = __builtin_amdgcn_mfma_f32_16x16x32_bf16(ahi[kt], b2l, acc2[ct], 0, 0, 0);
        }
    }
#pragma unroll
    for (int i = 0; i < 4; ++i) {
        const int row = r0 + lg * 4 + i;
        if (row < N) {
            uint4 u1, u2;
            u1.x = packh2(acc1[0][i], acc1[1][i]); u1.y = packh2(acc1[2][i], acc1[3][i]);
            u1.z = packh2(acc1[4][i], acc1[5][i]); u1.w = packh2(acc1[6][i], acc1[7][i]);
            u2.x = packh2(acc2[0][i], acc2[1][i]); u2.y = packh2(acc2[2][i], acc2[3][i]);
            u2.z = packh2(acc2[4][i], acc2[5][i]); u2.w = packh2(acc2[6][i], acc2[7][i]);
            *(uint4*)&P1[(size_t)row * 128 + l15 * 8] = u1;
            *(uint4*)&P2[(size_t)row * 128 + l15 * 8] = u2;
        }
    }
}

// proj_single: P = x_b@W2 (no bias), f16 interleaved; emits xb16.
__global__ __launch_bounds__(256) void proj_single_mfma(
    const float* __restrict__ X,
    const ushort_t* __restrict__ Bh, const ushort_t* __restrict__ Bl,
    ushort_t* __restrict__ P, ushort_t* __restrict__ X16, int N)
{
    const int lane = threadIdx.x & 63;
    const int l15 = lane & 15, lg = lane >> 4;
    const int r0 = blockIdx.x * 64 + (threadIdx.x >> 6) * 16;
    const int arow = (r0 + l15 < N) ? (r0 + l15) : (N - 1);

    bf16x8 ahi[4], alo[4];
#pragma unroll
    for (int kt = 0; kt < 4; ++kt) {
        float v[8];
        *(float4*)(v + 0) = *(const float4*)&X[(size_t)arow * 128 + kt * 32 + lg * 8];
        *(float4*)(v + 4) = *(const float4*)&X[(size_t)arow * 128 + kt * 32 + lg * 8 + 4];
        uint4 xu;
        xu.x = packh2(v[0], v[1]); xu.y = packh2(v[2], v[3]);
        xu.z = packh2(v[4], v[5]); xu.w = packh2(v[6], v[7]);
        *(uint4*)&X16[(size_t)arow * 128 + kt * 32 + lg * 8] = xu;
#pragma unroll
        for (int j = 0; j < 8; ++j) {
            const ushort_t h = bf16r(v[j]);
            ahi[kt][j] = (short)h;
            alo[kt][j] = (short)bf16r(v[j] - bf2f(h));
        }
    }

    f32x4 acc[8];
#pragma unroll
    for (int ct = 0; ct < 8; ++ct) acc[ct] = (f32x4){0.f, 0.f, 0.f, 0.f};

#pragma unroll
    for (int ct = 0; ct < 8; ++ct) {
#pragma unroll
        for (int kt = 0; kt < 4; ++kt) {
            const size_t fo = (size_t)((ct * 4 + kt) * 64 + lane) * 8;
            const bf16x8 bhf = *(const bf16x8*)&Bh[fo];
            const bf16x8 blf = *(const bf16x8*)&Bl[fo];
            acc[ct] = __builtin_amdgcn_mfma_f32_16x16x32_bf16(ahi[kt], bhf, acc[ct], 0, 0, 0);
            acc[ct] = __builtin_amdgcn_mfma_f32_16x16x32_bf16(alo[kt], bhf, acc[ct], 0, 0, 0);
            acc[ct] = __builtin_amdgcn_mfma_f32_16x16x32_bf16(ahi[kt], blf, acc[ct], 0, 0, 0);
        }
    }
#pragma unroll
    for (int i = 0; i < 4; ++i) {
        const int row = r0 + lg * 4 + i;
        if (row < N) {
            uint4 u;
            u.x = packh2(acc[0][i], acc[1][i]); u.y = packh2(acc[2][i], acc[3][i]);
            u.z = packh2(acc[4][i], acc[5][i]); u.w = packh2(acc[6][i], acc[7][i]);
            *(uint4*)&P[(size_t)row * 128 + l15 * 8] = u;
        }
    }
}

// ---------------------------------------------------------------------------
// Merged edge-score kernel, 512-thread blocks, decoupled:
//  - only Bh staged in LDS (16 KB); Bl read from global (L2-hot 16 KB)
//  - single (staging) barrier; NO trailing barrier: per-wave pm/pl
//  - CSR count+rank atomics issued AFTER compute
//  grid 5000: blocks [0,2500) -> AB (128 edges), [2500,5000) -> AA.
// NOTE: plain __launch_bounds__(512) — round 11's ",8" min-waves clamp
// forced 32 VGPR + 516 MB of scratch spill traffic (2.9x regression).
// ---------------------------------------------------------------------------
__global__ __launch_bounds__(512) void edge_score_k(
    const float* __restrict__ ea_ab, const float* __restrict__ ea_aa,
    const int*   __restrict__ ei_ab, const int*   __restrict__ ei_aa,
    const ushort_t* __restrict__ P1h,
    const ushort_t* __restrict__ P2ah, const ushort_t* __restrict__ P2bh,
    const ushort_t* __restrict__ Bhi,  const ushort_t* __restrict__ Blo,
    const float* __restrict__ wep,
    float* __restrict__ scAB, float* __restrict__ scAA,
    int* __restrict__ cntA, int* __restrict__ cntB,
    int* __restrict__ rkAab, int* __restrict__ rkBab, int* __restrict__ rkAaa,
    float* __restrict__ pm, float* __restrict__ pl)
{
    const int t    = threadIdx.x;
    const int lane = t & 63;
    const int l15  = lane & 15;
    const int lg   = lane >> 4;
    const int wv   = t >> 6;                        // 0..7
    const int type = (blockIdx.x >= 2500);
    const int bb   = type ? (blockIdx.x - 2500) : blockIdx.x;
    const int eb   = bb * 128;
    const int gw   = blockIdx.x * 8 + wv;           // per-wave partial slot

    const float* __restrict__ ea  = type ? ea_aa : ea_ab;
    const int*   __restrict__ ei  = type ? ei_aa : ei_ab;
    const ushort_t* __restrict__ P2h = type ? P2ah : P2bh;
    float* __restrict__ score = type ? scAA : scAB;

    __shared__ ushort_t sBh[8192];   // 16 KB = 1024 uint4 (Bh only)
    {
        const uint4* gh = (const uint4*)Bhi;   // 1024 uint4 total
        uint4* sh = (uint4*)sBh;
        sh[t]       = gh[t];          // t in [0,512)
        sh[t + 512] = gh[t + 512];    // both halves staged
    }

    const int e0 = eb + wv * 16;   // this wave's 16 edges

    // hoisted indices (int4) + P gathers (fly under A-conversion + MFMA)
    const int4 sv = *(const int4*)&ei[e0 + lg * 4];
    const int4 dv = *(const int4*)&ei[(size_t)E_AB + e0 + lg * 4];
    const int sidx[4] = {sv.x, sv.y, sv.z, sv.w};
    const int didx[4] = {dv.x, dv.y, dv.z, dv.w};
    uint4 p1u[4], p2u[4];
#pragma unroll
    for (int i = 0; i < 4; ++i) {
        p1u[i] = *(const uint4*)&P1h[(size_t)sidx[i] * 128 + l15 * 8];
        p2u[i] = *(const uint4*)&P2h[(size_t)didx[i] * 128 + l15 * 8];
    }

    float w8[8];
    *(float4*)(w8 + 0) = *(const float4*)&wep[l15 * 8];
    *(float4*)(w8 + 4) = *(const float4*)&wep[l15 * 8 + 4];

    // A fragment: row = l15 (edge e0+l15), k = kt*32 + lg*8 + j
    const float* arow = &ea[(size_t)(e0 + l15) * 64 + lg * 8];
    float af[16];
    *(float4*)(af + 0)  = *(const float4*)(arow + 0);
    *(float4*)(af + 4)  = *(const float4*)(arow + 4);
    *(float4*)(af + 8)  = *(const float4*)(arow + 32);
    *(float4*)(af + 12) = *(const float4*)(arow + 36);

    bf16x8 ahi0, alo0, ahi1, alo1;
#pragma unroll
    for (int j = 0; j < 8; ++j) {
        const ushort_t h0 = bf16r(af[j]);
        ahi0[j] = (short)h0;
        alo0[j] = (short)bf16r(af[j] - bf2f(h0));
        const ushort_t h1 = bf16r(af[8 + j]);
        ahi1[j] = (short)h1;
        alo1[j] = (short)bf16r(af[8 + j] - bf2f(h1));
    }

    __syncthreads();   // staging complete (only barrier in the kernel)

    f32x4 acc[8];
#pragma unroll
    for (int ct = 0; ct < 8; ++ct) acc[ct] = (f32x4){0.f, 0.f, 0.f, 0.f};

#pragma unroll
    for (int ct = 0; ct < 8; ++ct) {
        const bf16x8 bh0 = *(const bf16x8*)&sBh[(ct * 2 + 0) * 512 + lane * 8];
        const bf16x8 bh1 = *(const bf16x8*)&sBh[(ct * 2 + 1) * 512 + lane * 8];
        const bf16x8 bl0 = *(const bf16x8*)&Blo[(size_t)(ct * 2 + 0) * 512 + lane * 8];
        const bf16x8 bl1 = *(const bf16x8*)&Blo[(size_t)(ct * 2 + 1) * 512 + lane * 8];
        acc[ct] = __builtin_amdgcn_mfma_f32_16x16x32_bf16(ahi0, bh0, acc[ct], 0, 0, 0);
        acc[ct] = __builtin_amdgcn_mfma_f32_16x16x32_bf16(alo0, bh0, acc[ct], 0, 0, 0);
        acc[ct] = __builtin_amdgcn_mfma_f32_16x16x32_bf16(ahi0, bl0, acc[ct], 0, 0, 0);
        acc[ct] = __builtin_amdgcn_mfma_f32_16x16x32_bf16(ahi1, bh1, acc[ct], 0, 0, 0);
        acc[ct] = __builtin_amdgcn_mfma_f32_16x16x32_bf16(alo1, bh1, acc[ct], 0, 0, 0);
        acc[ct] = __builtin_amdgcn_mfma_f32_16x16x32_bf16(ahi1, bl1, acc[ct], 0, 0, 0);
    }

    float part[4];
#pragma unroll
    for (int i = 0; i < 4; ++i) {
        const __half2* h1 = (const __half2*)&p1u[i];
        const __half2* h2 = (const __half2*)&p2u[i];
        float p = 0.f;
#pragma unroll
        for (int q = 0; q < 4; ++q) {
            const float2 pf = __half22float2(__hadd2(h1[q], h2[q]));
            p = fmaf(fmaxf(acc[2 * q][i] + pf.x, 0.f), w8[2 * q], p);
            p = fmaf(fmaxf(acc[2 * q + 1][i] + pf.y, 0.f), w8[2 * q + 1], p);
        }
        part[i] = p;
    }
#pragma unroll
    for (int m = 8; m >= 1; m >>= 1) {
#pragma unroll
        for (int i = 0; i < 4; ++i) part[i] += __shfl_xor(part[i], m, 64);
    }
    if (l15 == 0) {
#pragma unroll
        for (int i = 0; i < 4; ++i) score[e0 + lg * 4 + i] = part[i];
    }

    // per-wave softmax partial (no cross-wave reduce, no barrier)
    float mw = fmaxf(fmaxf(part[0], part[1]), fmaxf(part[2], part[3]));
    float lw = __expf(part[0] - mw) + __expf(part[1] - mw)
             + __expf(part[2] - mw) + __expf(part[3] - mw);
#pragma unroll
    for (int off = 16; off <= 32; off <<= 1) {
        const float om = __shfl_xor(mw, off, 64);
        const float ol = __shfl_xor(lw, off, 64);
        online_merge(mw, lw, om, ol);
    }
    if (lane == 0) { pm[gw] = mw; pl[gw] = lw; }

    // CSR count + rank LAST (latency overlaps other blocks' compute)
    if (t < 128) {
        const int e = eb + t;
        const int s = ei[e];
        const int r = atomicAdd(&cntA[s], 1);
        if (type) rkAaa[e] = r; else rkAab[e] = r;
    } else if (t < 256 && !type) {
        const int e = eb + (t - 128);
        const int d = ei[(size_t)E_AB + e];
        rkBab[e] = atomicAdd(&cntB[d], 1);
    }
}

// ---------------------------------------------------------------------------
// Final softmax reduction over wave partials; grid 2 (type per block)
// ---------------------------------------------------------------------------
__global__ __launch_bounds__(1024) void softmax_final_kernel(
    const float* __restrict__ pm, const float* __restrict__ pl,
    float* __restrict__ ML, int nPart)
{
    const int type = blockIdx.x;
    const float* mi = pm + type * nPart;
    const float* li = pl + type * nPart;
    float m = -1e30f, l = 0.f;
    for (int i = threadIdx.x; i < nPart; i += 1024) online_merge(m, l, mi[i], li[i]);
#pragma unroll
    for (int off = 1; off < 64; off <<= 1) {
        const float om = __shfl_xor(m, off, 64);
        const float ol = __shfl_xor(l, off, 64);
        online_merge(m, l, om, ol);
    }
    __shared__ float smm[16], sll[16];
    const int w = threadIdx.x >> 6, lane = threadIdx.x & 63;
    if (lane == 0) { smm[w] = m; sll[w] = l; }
    __syncthreads();
    if (threadIdx.x == 0) {
        float M = smm[0], L = sll[0];
        for (int i = 1; i < 16; ++i) online_merge(M, L, smm[i], sll[i]);
        ML[type * 2]     = M;
        ML[type * 2 + 1] = L;
    }
}

// ---------------------------------------------------------------------------
// CSR scan
// ---------------------------------------------------------------------------
__global__ __launch_bounds__(1024) void csr_scan_kernel(
    const int* __restrict__ cntA, int* __restrict__ offA,
    const int* __restrict__ cntB, int* __restrict__ offB, int N)
{
    const int* cnt = (blockIdx.x == 0) ? cntA : cntB;
    int* off = (blockIdx.x == 0) ? offA : offB;

    __shared__ int warpsum[16];
    const int t = threadIdx.x, lane = t & 63, w = t >> 6;
    int carry = 0;

    for (int base = 0; base < N; base += 1024) {
        const int i = base + t;
        const int v = (i < N) ? cnt[i] : 0;
        int x = v;
#pragma unroll
        for (int d = 1; d < 64; d <<= 1) {
            const int y = __shfl_up(x, d, 64);
            if (lane >= d) x += y;
        }
        if (lane == 63) warpsum[w] = x;
        __syncthreads();
        if (w == 0 && lane < 16) {
            int s = warpsum[lane];
#pragma unroll
            for (int d = 1; d < 16; d <<= 1) {
                const int y = __shfl_up(s, d, 64);
                if (lane >= d) s += y;
            }
            warpsum[lane] = s;
        }
        __syncthreads();
        const int excl = (x - v) + ((w > 0) ? warpsum[w - 1] : 0) + carry;
        if (i < N) off[i] = excl;
        carry += warpsum[15];
        __syncthreads();
    }
    if (t == 0) off[N] = carry;
}

// Atomic-free fill with fused softmax normalization (positions clamped for
// rocprof-replay atomic-inflation safety).
__global__ __launch_bounds__(256) void csr_fill_kernel(
    const int* __restrict__ ei_ab, const int* __restrict__ ei_aa,
    float* __restrict__ scAB, float* __restrict__ scAA,
    const float* __restrict__ ML,
    const int* __restrict__ offA, const int* __restrict__ offB,
    const int* __restrict__ rkAab, const int* __restrict__ rkBab,
    const int* __restrict__ rkAaa,
    int2* __restrict__ idxA, int2* __restrict__ idxB)
{
    const int i = blockIdx.x * 256 + threadIdx.x;
    const float Mab = ML[0], rLab = 1.0f / ML[1];
    const float Maa = ML[2], rLaa = 1.0f / ML[3];
    if (i < E_AB) {
        const float a = __expf(scAB[i] - Mab) * rLab;
        scAB[i] = a;
        const int s = ei_ab[i], d = ei_ab[E_AB + i];
        const int ab = __float_as_int(a);
        int pA = offA[s] + rkAab[i]; if (pA > 2 * E_AB - 1) pA = 2 * E_AB - 1;
        int pB = offB[d] + rkBab[i]; if (pB > E_AB - 1) pB = E_AB - 1;
        idxA[pA] = make_int2(d | (1 << 20), ab);
        idxB[pB] = make_int2(s, ab);
    }
    if (i < E_AA) {
        const float a = __expf(scAA[i] - Maa) * rLaa;
        scAA[i] = a;
        const int s = ei_aa[i];
        const int daa = ei_aa[E_AA + i];
        int pA = offA[s] + rkAaa[i]; if (pA > 2 * E_AB - 1) pA = 2 * E_AB - 1;
        idxA[pA] = make_int2(daa, __float_as_int(a));
    }
}

// ---------------------------------------------------------------------------
// Fused gather + final. Phase 1: quarter-wave per row, 4-wide entry unroll.
// Phase 2: final MFMA (T <- T + T@FT + fb) on the same 16 rows (L2-hot).
// ---------------------------------------------------------------------------
__global__ __launch_bounds__(256) void gather_final(
    const int*  __restrict__ off, const int2* __restrict__ idx,
    const ushort_t* __restrict__ xa16, const ushort_t* __restrict__ xb16,
    const float* __restrict__ xself,
    const ushort_t* __restrict__ Bh, const ushort_t* __restrict__ Bl,
    const float* __restrict__ fb,
    float* __restrict__ T, int N)
{
    const int lane = threadIdx.x & 63;
    const int l15  = lane & 15, lg = lane >> 4;
    const int wv   = threadIdx.x >> 6;
    const int r0   = blockIdx.x * 64 + wv * 16;

    for (int s = 0; s < 4; ++s) {
        const int row = r0 + s * 4 + lg;
        if (row < N) {
            const int beg = off[row], end = off[row + 1];
            float a8[8];
            *(float4*)(a8 + 0) = *(const float4*)&xself[(size_t)row * 128 + l15 * 8];
            *(float4*)(a8 + 4) = *(const float4*)&xself[(size_t)row * 128 + l15 * 8 + 4];
            int e = beg;
            for (; e + 3 < end; e += 4) {
                int2 q[4];
#pragma unroll
                for (int k = 0; k < 4; ++k) q[k] = idx[e + k];
                uint4 f[4];
#pragma unroll
                for (int k = 0; k < 4; ++k) {
                    const ushort_t* sp = (q[k].x & (1 << 20)) ? xb16 : xa16;
                    f[k] = *(const uint4*)&sp[(size_t)(q[k].x & 0xFFFFF) * 128 + l15 * 8];
                }
#pragma unroll
                for (int k = 0; k < 4; ++k) {
                    const float al = __int_as_float(q[k].y);
                    const __half2* hp = (const __half2*)&f[k];
#pragma unroll
                    for (int j = 0; j < 4; ++j) {
                        const float2 vf = __half22float2(hp[j]);
                        a8[2 * j]     = fmaf(-al, vf.x, a8[2 * j]);
                        a8[2 * j + 1] = fmaf(-al, vf.y, a8[2 * j + 1]);
                    }
                }
            }
            for (; e < end; ++e) {
                const int2 q0 = idx[e];
                const float al = __int_as_float(q0.y);
                const ushort_t* sp = (q0.x & (1 << 20)) ? xb16 : xa16;
                const uint4 f0 = *(const uint4*)&sp[(size_t)(q0.x & 0xFFFFF) * 128 + l15 * 8];
                const __half2* hp = (const __half2*)&f0;
#pragma unroll
                for (int j = 0; j < 4; ++j) {
                    const float2 vf = __half22float2(hp[j]);
                    a8[2 * j]     = fmaf(-al, vf.x, a8[2 * j]);
                    a8[2 * j + 1] = fmaf(-al, vf.y, a8[2 * j + 1]);
                }
            }
            *(float4*)&T[(size_t)row * 128 + l15 * 8]     = *(float4*)(a8 + 0);
            *(float4*)&T[(size_t)row * 128 + l15 * 8 + 4] = *(float4*)(a8 + 4);
        }
    }
    __syncthreads();

    const int arow = (r0 + l15 < N) ? (r0 + l15) : (N - 1);
    bf16x8 ahi[4], alo[4];
#pragma unroll
    for (int kt = 0; kt < 4; ++kt) {
        float v[8];
        *(float4*)(v + 0) = *(const float4*)&T[(size_t)arow * 128 + kt * 32 + lg * 8];
        *(float4*)(v + 4) = *(const float4*)&T[(size_t)arow * 128 + kt * 32 + lg * 8 + 4];
#pragma unroll
        for (int j = 0; j < 8; ++j) {
            const ushort_t h = bf16r(v[j]);
            ahi[kt][j] = (short)h;
            alo[kt][j] = (short)bf16r(v[j] - bf2f(h));
        }
    }

    f32x4 acc[8];
#pragma unroll
    for (int ct = 0; ct < 8; ++ct) {
        const float b = fb[ct * 16 + l15];
#pragma unroll
        for (int i = 0; i < 4; ++i) {
            const int row = r0 + lg * 4 + i;
            const int rr = (row < N) ? row : (N - 1);
            acc[ct][i] = T[(size_t)rr * 128 + ct * 16 + l15] + b;
        }
    }

#pragma unroll
    for (int ct = 0; ct < 8; ++ct) {
#pragma unroll
        for (int kt = 0; kt < 4; ++kt) {
            const size_t fo = (size_t)((ct * 4 + kt) * 64 + lane) * 8;
            const bf16x8 bhf = *(const bf16x8*)&Bh[fo];
            const bf16x8 blf = *(const bf16x8*)&Bl[fo];
            acc[ct] = __builtin_amdgcn_mfma_f32_16x16x32_bf16(ahi[kt], bhf, acc[ct], 0, 0, 0);
            acc[ct] = __builtin_amdgcn_mfma_f32_16x16x32_bf16(alo[kt], bhf, acc[ct], 0, 0, 0);
            acc[ct] = __builtin_amdgcn_mfma_f32_16x16x32_bf16(ahi[kt], blf, acc[ct], 0, 0, 0);
        }
    }
#pragma unroll
    for (int ct = 0; ct < 8; ++ct) {
#pragma unroll
        for (int i = 0; i < 4; ++i) {
            const int row = r0 + lg * 4 + i;
            if (row < N) T[(size_t)row * 128 + ct * 16 + l15] = acc[ct][i];
        }
    }
}

// ---------------------------------------------------------------------------
extern "C" void kernel_launch(void* const* d_in, const int* in_sizes, int n_in,
                              void* d_out, int out_size, void* d_ws, size_t ws_size,
                              hipStream_t stream)
{
    const float* x_a   = (const float*)d_in[0];
    const float* x_b   = (const float*)d_in[1];
    const int*   ei_ab = (const int*)d_in[2];
    const float* ea_ab = (const float*)d_in[3];
    const int*   ei_aa = (const int*)d_in[4];
    const float* ea_aa = (const float*)d_in[5];
    const float* Wh_w  = (const float*)d_in[6];
    const float* Wh_b  = (const float*)d_in[7];
    const float* Wn_w  = (const float*)d_in[8];
    const float* Wn_b  = (const float*)d_in[9];
    const float* w_e   = (const float*)d_in[10];
    const float* ft_w  = (const float*)d_in[11];
    const float* ft_b  = (const float*)d_in[12];

    float* out = (float*)d_out;
    float* ws  = (float*)d_ws;

    // ws layout (float offsets; all regions disjoint)
    ushort_t* P1h  = (ushort_t*)(ws);              // 6.4M ushorts
    ushort_t* P2ah = (ushort_t*)(ws + 3200000);
    ushort_t* P2bh = (ushort_t*)(ws + 6400000);
    ushort_t* xa16 = (ushort_t*)(ws + 9600000);
    ushort_t* xb16 = (ushort_t*)(ws + 12800000);
    int* rkAab = (int*)(ws + 16000000);
    int* rkBab = (int*)(ws + 16320000);
    int* rkAaa = (int*)(ws + 16640000);
    int* cntA  = (int*)(ws + 16960000);            // cntA+cntB contiguous
    int* cntB  = (int*)(ws + 17010000);
    int* offA  = (int*)(ws + 17060000);            // 50001
    int* offB  = (int*)(ws + 17110004);            // 50001
    float* pm  = ws + 17160008;                    // 40000 (20000 per type)
    float* pl  = ws + 17200008;                    // 40000
    float* ML  = ws + 17240008;                    // 4
    float* wep = ws + 17240016;                    // 128
    ushort_t* FR = (ushort_t*)(ws + 17240208);     // 114688 ushorts
    ushort_t* BhWh = FR;
    ushort_t* BlWh = FR + 8192;
    ushort_t* BhW1 = FR + 16384;
    ushort_t* BlW1 = FR + 32768;
    ushort_t* BhW2 = FR + 49152;
    ushort_t* BlW2 = FR + 65536;
    ushort_t* BhFT = FR + 81920;
    ushort_t* BlFT = FR + 98304;                   // ends ws+17297552
    int2* idxA = (int2*)(ws + 17300000);           // 640000 entries
    int2* idxB = (int2*)(ws + 18580000);           // 320000 entries -> 19220000

    // d_out layout: out_a[6.4M] out_b[6.4M] alpha_ab[320K] alpha_aa[320K]
    float* TA   = out;
    float* TB   = out + 6400000;
    float* alAB = out + 12800000;   // raw scores, then normalized in csr_fill
    float* alAA = out + 13120000;

    // 0) zero CSR counters; pack weights
    hipMemsetAsync(cntA, 0, 100000 * sizeof(int), stream);
    prep_w_all<<<113, 64, 0, stream>>>(Wh_w, Wn_w, Wn_w + 128 * 128, ft_w, w_e,
                                       BhWh, BlWh, BhW1, BlW1, BhW2, BlW2, BhFT, BlFT, wep);

    // 1) node projections (f16 tables, interleaved layout) + f16 x copies
    proj_dual_mfma<<<(N_A + 63) / 64, 256, 0, stream>>>(x_a, BhW1, BlW1, BhW2, BlW2,
                                                        Wh_b, Wn_b, P1h, P2ah, xa16, N_A);
    proj_single_mfma<<<(N_B + 63) / 64, 256, 0, stream>>>(x_b, BhW2, BlW2, P2bh, xb16, N_B);

    // 2) merged edge scores, decoupled 512-thread blocks (no VGPR clamp)
    edge_score_k<<<5000, 512, 0, stream>>>(ea_ab, ea_aa, ei_ab, ei_aa,
                                           P1h, P2ah, P2bh, BhWh, BlWh, wep,
                                           alAB, alAA, cntA, cntB,
                                           rkAab, rkBab, rkAaa, pm, pl);

    // 3) softmax final reduction (both types; 20000 wave partials each)
    softmax_final_kernel<<<2, 1024, 0, stream>>>(pm, pl, ML, 20000);

    // 4) CSR scan + atomic-free fill (fused normalization)
    csr_scan_kernel<<<2, 1024, 0, stream>>>(cntA, offA, cntB, offB, N_A);
    csr_fill_kernel<<<(E_AB + 255) / 256, 256, 0, stream>>>(ei_ab, ei_aa, alAB, alAA, ML,
                                                            offA, offB, rkAab, rkBab, rkAaa,
                                                            idxA, idxB);

    // 5) fused gather + final transform
    gather_final<<<(N_A + 63) / 64, 256, 0, stream>>>(offA, idxA, xa16, xb16, x_a,
                                                      BhFT, BlFT, ft_b, TA, N_A);
    gather_final<<<(N_B + 63) / 64, 256, 0, stream>>>(offB, idxB, xa16, xb16, x_b,
                                                      BhFT, BlFT, ft_b, TB, N_B);

    (void)in_sizes; (void)n_in; (void)out_size; (void)ws_size;
}

// Round 13
// 358.886 us; speedup vs baseline: 1.4563x; 1.0471x over previous
//
#include <hip/hip_runtime.h>
#include <hip/hip_fp16.h>
#include <cstdint>
#include <cstddef>

// Problem constants (fixed by the reference)
#define N_A   50000
#define N_B   50000
#define E_AB  320000
#define E_AA  320000
#define IN_DIM 128
#define HID    128
#define ED     64
#define BKT_CAP 28   // per-node bucket capacity; degree ~ Poisson(6.4), max ~22

using bf16x8 = __attribute__((ext_vector_type(8))) short;
using f32x4  = __attribute__((ext_vector_type(4))) float;
typedef unsigned short ushort_t;
typedef unsigned int   uint_t;

__device__ inline ushort_t bf16r(float f) {   // f32 -> bf16 bits, RNE
    uint_t u = __float_as_uint(f);
    u = (u + 0x7FFF + ((u >> 16) & 1)) >> 16;
    return (ushort_t)u;
}
__device__ inline float bf2f(ushort_t h) {
    return __uint_as_float(((uint_t)h) << 16);
}
__device__ inline ushort_t f16r(float f) { return __half_as_ushort(__float2half_rn(f)); }
__device__ inline float f16f(ushort_t u) { return __half2float(__ushort_as_half(u)); }
__device__ inline uint_t packh2(float a, float b) {
    return (uint_t)f16r(a) | ((uint_t)f16r(b) << 16);
}

__device__ inline void online_merge(float& m, float& l, float om, float ol) {
    const float nm = fmaxf(m, om);
    l = l * __expf(m - nm) + ol * __expf(om - nm);
    m = nm;
}

// ---------------------------------------------------------------------------
// Pre-pack all weights into bf16 hi/lo MFMA B-fragments + permuted w_e.
// ---------------------------------------------------------------------------
__global__ __launch_bounds__(64) void prep_w_all(
    const float* __restrict__ Wh, const float* __restrict__ W1,
    const float* __restrict__ W2, const float* __restrict__ FT,
    const float* __restrict__ we,
    ushort_t* __restrict__ BhWh, ushort_t* __restrict__ BlWh,
    ushort_t* __restrict__ BhW1, ushort_t* __restrict__ BlW1,
    ushort_t* __restrict__ BhW2, ushort_t* __restrict__ BlW2,
    ushort_t* __restrict__ BhFT, ushort_t* __restrict__ BlFT,
    float* __restrict__ wep)
{
    const int f = blockIdx.x;
    const int lane = threadIdx.x;
    if (f == 112) {
#pragma unroll
        for (int q = 0; q < 2; ++q) {
            const int idx = lane + q * 64;
            const int l15 = idx >> 3, ct = idx & 7;
            wep[idx] = we[ct * 16 + l15];
        }
        return;
    }
    const float* W; ushort_t *oh, *ol; int KT, fl;
    if (f < 16)      { W = Wh; oh = BhWh; ol = BlWh; KT = 2; fl = f; }
    else if (f < 48) { W = W1; oh = BhW1; ol = BlW1; KT = 4; fl = f - 16; }
    else if (f < 80) { W = W2; oh = BhW2; ol = BlW2; KT = 4; fl = f - 48; }
    else             { W = FT; oh = BhFT; ol = BlFT; KT = 4; fl = f - 80; }
    const int ct = fl / KT, kt = fl % KT;
    const int col = ct * 16 + (lane & 15);
    const int kb  = kt * 32 + (lane >> 4) * 8;
#pragma unroll
    for (int j = 0; j < 8; ++j) {
        const float v = W[(kb + j) * 128 + col];
        const ushort_t h = bf16r(v);
        oh[(size_t)(fl * 64 + lane) * 8 + j] = h;
        ol[(size_t)(fl * 64 + lane) * 8 + j] = bf16r(v - bf2f(h));
    }
}

// ---------------------------------------------------------------------------
// proj_dual: P1 = x_a@W1 + (bh+bn), P2 = x_a@W2, f16 interleaved; emits xa16.
// ---------------------------------------------------------------------------
__global__ __launch_bounds__(256) void proj_dual_mfma(
    const float* __restrict__ X,
    const ushort_t* __restrict__ B1h, const ushort_t* __restrict__ B1l,
    const ushort_t* __restrict__ B2h, const ushort_t* __restrict__ B2l,
    const float* __restrict__ bh, const float* __restrict__ bn,
    ushort_t* __restrict__ P1, ushort_t* __restrict__ P2,
    ushort_t* __restrict__ X16, int N)
{
    const int lane = threadIdx.x & 63;
    const int l15 = lane & 15, lg = lane >> 4;
    const int r0 = blockIdx.x * 64 + (threadIdx.x >> 6) * 16;
    const int arow = (r0 + l15 < N) ? (r0 + l15) : (N - 1);

    bf16x8 ahi[4], alo[4];
#pragma unroll
    for (int kt = 0; kt < 4; ++kt) {
        float v[8];
        *(float4*)(v + 0) = *(const float4*)&X[(size_t)arow * 128 + kt * 32 + lg * 8];
        *(float4*)(v + 4) = *(const float4*)&X[(size_t)arow * 128 + kt * 32 + lg * 8 + 4];
        uint4 xu;
        xu.x = packh2(v[0], v[1]); xu.y = packh2(v[2], v[3]);
        xu.z = packh2(v[4], v[5]); xu.w = packh2(v[6], v[7]);
        *(uint4*)&X16[(size_t)arow * 128 + kt * 32 + lg * 8] = xu;
#pragma unroll
        for (int j = 0; j < 8; ++j) {
            const ushort_t h = bf16r(v[j]);
            ahi[kt][j] = (short)h;
            alo[kt][j] = (short)bf16r(v[j] - bf2f(h));
        }
    }

    f32x4 acc1[8], acc2[8];
#pragma unroll
    for (int ct = 0; ct < 8; ++ct) {
        const float b = bh[ct * 16 + l15] + bn[ct * 16 + l15];
        acc1[ct] = (f32x4){b, b, b, b};
        acc2[ct] = (f32x4){0.f, 0.f, 0.f, 0.f};
    }

#pragma unroll
    for (int ct = 0; ct < 8; ++ct) {
#pragma unroll
        for (int kt = 0; kt < 4; ++kt) {
            const size_t fo = (size_t)((ct * 4 + kt) * 64 + lane) * 8;
            const bf16x8 b1h = *(const bf16x8*)&B1h[fo];
            const bf16x8 b1l = *(const bf16x8*)&B1l[fo];
            const bf16x8 b2h = *(const bf16x8*)&B2h[fo];
            const bf16x8 b2l = *(const bf16x8*)&B2l[fo];
            acc1[ct] = __builtin_amdgcn_mfma_f32_16x16x32_bf16(ahi[kt], b1h, acc1[ct], 0, 0, 0);
            acc1[ct] = __builtin_amdgcn_mfma_f32_16x16x32_bf16(alo[kt], b1h, acc1[ct], 0, 0, 0);
            acc1[ct] = __builtin_amdgcn_mfma_f32_16x16x32_bf16(ahi[kt], b1l, acc1[ct], 0, 0, 0);
            acc2[ct] = __builtin_amdgcn_mfma_f32_16x16x32_bf16(ahi[kt], b2h, acc2[ct], 0, 0, 0);
            acc2[ct] = __builtin_amdgcn_mfma_f32_16x16x32_bf16(alo[kt], b2h, acc2[ct], 0, 0, 0);
            acc2[ct] = __builtin_amdgcn_mfma_f32_16x16x32_bf16(ahi[kt], b2l, acc2[ct], 0, 0, 0);
        }
    }
#pragma unroll
    for (int i = 0; i < 4; ++i) {
        const int row = r0 + lg * 4 + i;
        if (row < N) {
            uint4 u1, u2;
            u1.x = packh2(acc1[0][i], acc1[1][i]); u1.y = packh2(acc1[2][i], acc1[3][i]);
            u1.z = packh2(acc1[4][i], acc1[5][i]); u1.w = packh2(acc1[6][i], acc1[7][i]);
            u2.x = packh2(acc2[0][i], acc2[1][i]); u2.y = packh2(acc2[2][i], acc2[3][i]);
            u2.z = packh2(acc2[4][i], acc2[5][i]); u2.w = packh2(acc2[6][i], acc2[7][i]);
            *(uint4*)&P1[(size_t)row * 128 + l15 * 8] = u1;
            *(uint4*)&P2[(size_t)row * 128 + l15 * 8] = u2;
        }
    }
}

// proj_single: P = x_b@W2 (no bias), f16 interleaved; emits xb16.
__global__ __launch_bounds__(256) void proj_single_mfma(
    const float* __restrict__ X,
    const ushort_t* __restrict__ Bh, const ushort_t* __restrict__ Bl,
    ushort_t* __restrict__ P, ushort_t* __restrict__ X16, int N)
{
    const int lane = threadIdx.x & 63;
    const int l15 = lane & 15, lg = lane >> 4;
    const int r0 = blockIdx.x * 64 + (threadIdx.x >> 6) * 16;
    const int arow = (r0 + l15 < N) ? (r0 + l15) : (N - 1);

    bf16x8 ahi[4], alo[4];
#pragma unroll
    for (int kt = 0; kt < 4; ++kt) {
        float v[8];
        *(float4*)(v + 0) = *(const float4*)&X[(size_t)arow * 128 + kt * 32 + lg * 8];
        *(float4*)(v + 4) = *(const float4*)&X[(size_t)arow * 128 + kt * 32 + lg * 8 + 4];
        uint4 xu;
        xu.x = packh2(v[0], v[1]); xu.y = packh2(v[2], v[3]);
        xu.z = packh2(v[4], v[5]); xu.w = packh2(v[6], v[7]);
        *(uint4*)&X16[(size_t)arow * 128 + kt * 32 + lg * 8] = xu;
#pragma unroll
        for (int j = 0; j < 8; ++j) {
            const ushort_t h = bf16r(v[j]);
            ahi[kt][j] = (short)h;
            alo[kt][j] = (short)bf16r(v[j] - bf2f(h));
        }
    }

    f32x4 acc[8];
#pragma unroll
    for (int ct = 0; ct < 8; ++ct) acc[ct] = (f32x4){0.f, 0.f, 0.f, 0.f};

#pragma unroll
    for (int ct = 0; ct < 8; ++ct) {
#pragma unroll
        for (int kt = 0; kt < 4; ++kt) {
            const size_t fo = (size_t)((ct * 4 + kt) * 64 + lane) * 8;
            const bf16x8 bhf = *(const bf16x8*)&Bh[fo];
            const bf16x8 blf = *(const bf16x8*)&Bl[fo];
            acc[ct] = __builtin_amdgcn_mfma_f32_16x16x32_bf16(ahi[kt], bhf, acc[ct], 0, 0, 0);
            acc[ct] = __builtin_amdgcn_mfma_f32_16x16x32_bf16(alo[kt], bhf, acc[ct], 0, 0, 0);
            acc[ct] = __builtin_amdgcn_mfma_f32_16x16x32_bf16(ahi[kt], blf, acc[ct], 0, 0, 0);
        }
    }
#pragma unroll
    for (int i = 0; i < 4; ++i) {
        const int row = r0 + lg * 4 + i;
        if (row < N) {
            uint4 u;
            u.x = packh2(acc[0][i], acc[1][i]); u.y = packh2(acc[2][i], acc[3][i]);
            u.z = packh2(acc[4][i], acc[5][i]); u.w = packh2(acc[6][i], acc[7][i]);
            *(uint4*)&P[(size_t)row * 128 + l15 * 8] = u;
        }
    }
}

// ---------------------------------------------------------------------------
// Merged edge-score kernel (round-9 body: both B halves in LDS), with inline
// bucketed-CSR epilogue: l15==0 lanes hold each edge's score + s/d indices in
// registers, so they write per-node bucket entries (src | f16(score)<<16)
// directly — no rank arrays, no scan, no fill kernel.
// grid 5000: blocks [0,2500) -> AB (128 edges), [2500,5000) -> AA.
// ---------------------------------------------------------------------------
__global__ __launch_bounds__(512) void edge_score_k(
    const float* __restrict__ ea_ab, const float* __restrict__ ea_aa,
    const int*   __restrict__ ei_ab, const int*   __restrict__ ei_aa,
    const ushort_t* __restrict__ P1h,
    const ushort_t* __restrict__ P2ah, const ushort_t* __restrict__ P2bh,
    const ushort_t* __restrict__ Bhi,  const ushort_t* __restrict__ Blo,
    const float* __restrict__ wep,
    float* __restrict__ scAB, float* __restrict__ scAA,
    int* __restrict__ cntAab, int* __restrict__ cntAaa, int* __restrict__ cntB,
    uint_t* __restrict__ bktAab, uint_t* __restrict__ bktAaa, uint_t* __restrict__ bktB,
    float* __restrict__ pm, float* __restrict__ pl)
{
    const int t    = threadIdx.x;
    const int lane = t & 63;
    const int l15  = lane & 15;
    const int lg   = lane >> 4;
    const int wv   = t >> 6;                        // 0..7
    const int type = (blockIdx.x >= 2500);
    const int bb   = type ? (blockIdx.x - 2500) : blockIdx.x;
    const int eb   = bb * 128;
    const int gw   = blockIdx.x * 8 + wv;           // per-wave partial slot

    const float* __restrict__ ea  = type ? ea_aa : ea_ab;
    const int*   __restrict__ ei  = type ? ei_aa : ei_ab;
    const ushort_t* __restrict__ P2h = type ? P2ah : P2bh;
    float* __restrict__ score = type ? scAA : scAB;

    __shared__ ushort_t sBh[8192];   // 16 KB (1024 uint4)
    __shared__ ushort_t sBl[8192];   // 16 KB
    {
        const uint4* gh = (const uint4*)Bhi;
        const uint4* gl = (const uint4*)Blo;
        uint4* sh = (uint4*)sBh;
        uint4* sl = (uint4*)sBl;
#pragma unroll
        for (int i = 0; i < 2; ++i) {
            sh[t + i * 512] = gh[t + i * 512];
            sl[t + i * 512] = gl[t + i * 512];
        }
    }

    const int e0 = eb + wv * 16;   // this wave's 16 edges

    // hoisted indices (int4) + P gathers (fly under A-conversion + MFMA)
    const int4 sv = *(const int4*)&ei[e0 + lg * 4];
    const int4 dv = *(const int4*)&ei[(size_t)E_AB + e0 + lg * 4];
    const int sidx[4] = {sv.x, sv.y, sv.z, sv.w};
    const int didx[4] = {dv.x, dv.y, dv.z, dv.w};
    uint4 p1u[4], p2u[4];
#pragma unroll
    for (int i = 0; i < 4; ++i) {
        p1u[i] = *(const uint4*)&P1h[(size_t)sidx[i] * 128 + l15 * 8];
        p2u[i] = *(const uint4*)&P2h[(size_t)didx[i] * 128 + l15 * 8];
    }

    float w8[8];
    *(float4*)(w8 + 0) = *(const float4*)&wep[l15 * 8];
    *(float4*)(w8 + 4) = *(const float4*)&wep[l15 * 8 + 4];

    // A fragment: row = l15 (edge e0+l15), k = kt*32 + lg*8 + j
    const float* arow = &ea[(size_t)(e0 + l15) * 64 + lg * 8];
    float af[16];
    *(float4*)(af + 0)  = *(const float4*)(arow + 0);
    *(float4*)(af + 4)  = *(const float4*)(arow + 4);
    *(float4*)(af + 8)  = *(const float4*)(arow + 32);
    *(float4*)(af + 12) = *(const float4*)(arow + 36);

    bf16x8 ahi0, alo0, ahi1, alo1;
#pragma unroll
    for (int j = 0; j < 8; ++j) {
        const ushort_t h0 = bf16r(af[j]);
        ahi0[j] = (short)h0;
        alo0[j] = (short)bf16r(af[j] - bf2f(h0));
        const ushort_t h1 = bf16r(af[8 + j]);
        ahi1[j] = (short)h1;
        alo1[j] = (short)bf16r(af[8 + j] - bf2f(h1));
    }

    __syncthreads();   // LDS staging complete (only barrier in the kernel)

    f32x4 acc[8];
#pragma unroll
    for (int ct = 0; ct < 8; ++ct) acc[ct] = (f32x4){0.f, 0.f, 0.f, 0.f};

#pragma unroll
    for (int ct = 0; ct < 8; ++ct) {
        const bf16x8 bh0 = *(const bf16x8*)&sBh[(ct * 2 + 0) * 512 + lane * 8];
        const bf16x8 bl0 = *(const bf16x8*)&sBl[(ct * 2 + 0) * 512 + lane * 8];
        const bf16x8 bh1 = *(const bf16x8*)&sBh[(ct * 2 + 1) * 512 + lane * 8];
        const bf16x8 bl1 = *(const bf16x8*)&sBl[(ct * 2 + 1) * 512 + lane * 8];
        acc[ct] = __builtin_amdgcn_mfma_f32_16x16x32_bf16(ahi0, bh0, acc[ct], 0, 0, 0);
        acc[ct] = __builtin_amdgcn_mfma_f32_16x16x32_bf16(alo0, bh0, acc[ct], 0, 0, 0);
        acc[ct] = __builtin_amdgcn_mfma_f32_16x16x32_bf16(ahi0, bl0, acc[ct], 0, 0, 0);
        acc[ct] = __builtin_amdgcn_mfma_f32_16x16x32_bf16(ahi1, bh1, acc[ct], 0, 0, 0);
        acc[ct] = __builtin_amdgcn_mfma_f32_16x16x32_bf16(alo1, bh1, acc[ct], 0, 0, 0);
        acc[ct] = __builtin_amdgcn_mfma_f32_16x16x32_bf16(ahi1, bl1, acc[ct], 0, 0, 0);
    }

    float part[4];
#pragma unroll
    for (int i = 0; i < 4; ++i) {
        const __half2* h1 = (const __half2*)&p1u[i];
        const __half2* h2 = (const __half2*)&p2u[i];
        float p = 0.f;
#pragma unroll
        for (int q = 0; q < 4; ++q) {
            const float2 pf = __half22float2(__hadd2(h1[q], h2[q]));
            p = fmaf(fmaxf(acc[2 * q][i] + pf.x, 0.f), w8[2 * q], p);
            p = fmaf(fmaxf(acc[2 * q + 1][i] + pf.y, 0.f), w8[2 * q + 1], p);
        }
        part[i] = p;
    }
#pragma unroll
    for (int m = 8; m >= 1; m >>= 1) {
#pragma unroll
        for (int i = 0; i < 4; ++i) part[i] += __shfl_xor(part[i], m, 64);
    }

    if (l15 == 0) {
        // raw scores to d_out alpha slots (alpha_norm normalizes later)
#pragma unroll
        for (int i = 0; i < 4; ++i) score[e0 + lg * 4 + i] = part[i];
        // inline bucketed CSR: entry = src_row | f16(score) << 16
#pragma unroll
        for (int i = 0; i < 4; ++i) {
            const int s = sidx[i];
            const int d = didx[i];
            const uint_t us = (uint_t)f16r(part[i]) << 16;
            if (type == 0) {
                const int rA = atomicAdd(&cntAab[s], 1);
                if (rA < BKT_CAP) bktAab[s * BKT_CAP + rA] = (uint_t)d | us;
                const int rB = atomicAdd(&cntB[d], 1);
                if (rB < BKT_CAP) bktB[d * BKT_CAP + rB] = (uint_t)s | us;
            } else {
                const int rA = atomicAdd(&cntAaa[s], 1);
                if (rA < BKT_CAP) bktAaa[s * BKT_CAP + rA] = (uint_t)d | us;
            }
        }
    }

    // per-wave softmax partial (no cross-wave reduce, no trailing barrier)
    float mw = fmaxf(fmaxf(part[0], part[1]), fmaxf(part[2], part[3]));
    float lw = __expf(part[0] - mw) + __expf(part[1] - mw)
             + __expf(part[2] - mw) + __expf(part[3] - mw);
#pragma unroll
    for (int off = 16; off <= 32; off <<= 1) {
        const float om = __shfl_xor(mw, off, 64);
        const float ol = __shfl_xor(lw, off, 64);
        online_merge(mw, lw, om, ol);
    }
    if (lane == 0) { pm[gw] = mw; pl[gw] = lw; }
}

// ---------------------------------------------------------------------------
// Final softmax reduction over wave partials; grid 2 (type per block)
// ---------------------------------------------------------------------------
__global__ __launch_bounds__(1024) void softmax_final_kernel(
    const float* __restrict__ pm, const float* __restrict__ pl,
    float* __restrict__ ML, int nPart)
{
    const int type = blockIdx.x;
    const float* mi = pm + type * nPart;
    const float* li = pl + type * nPart;
    float m = -1e30f, l = 0.f;
    for (int i = threadIdx.x; i < nPart; i += 1024) online_merge(m, l, mi[i], li[i]);
#pragma unroll
    for (int off = 1; off < 64; off <<= 1) {
        const float om = __shfl_xor(m, off, 64);
        const float ol = __shfl_xor(l, off, 64);
        online_merge(m, l, om, ol);
    }
    __shared__ float smm[16], sll[16];
    const int w = threadIdx.x >> 6, lane = threadIdx.x & 63;
    if (lane == 0) { smm[w] = m; sll[w] = l; }
    __syncthreads();
    if (threadIdx.x == 0) {
        float M = smm[0], L = sll[0];
        for (int i = 1; i < 16; ++i) online_merge(M, L, smm[i], sll[i]);
        ML[type * 2]     = M;
        ML[type * 2 + 1] = L;
    }
}

// ---------------------------------------------------------------------------
// Alpha normalization (in place on the d_out alpha slots)
// ---------------------------------------------------------------------------
__global__ __launch_bounds__(256) void alpha_norm_kernel(
    float* __restrict__ scAB, float* __restrict__ scAA,
    const float* __restrict__ ML)
{
    const int i = blockIdx.x * 256 + threadIdx.x;
    const float Mab = ML[0], rLab = 1.0f / ML[1];
    const float Maa = ML[2], rLaa = 1.0f / ML[3];
    if (i < E_AB) scAB[i] = __expf(scAB[i] - Mab) * rLab;
    if (i < E_AA) scAA[i] = __expf(scAA[i] - Maa) * rLaa;
}

// ---------------------------------------------------------------------------
// Fused gather + final. Phase 1: quarter-wave per row, up to 2 buckets per
// row (entry = src | f16(score)<<16; alpha = exp(sc - M) / L per entry).
// Phase 2: final MFMA (T <- T + T@FT + fb) on the same 16 rows (L2-hot).
// ---------------------------------------------------------------------------
__global__ __launch_bounds__(256) void gather_final(
    const int* __restrict__ cnt0, const uint_t* __restrict__ bkt0,
    const ushort_t* __restrict__ x0,
    const int* __restrict__ cnt1, const uint_t* __restrict__ bkt1,
    const ushort_t* __restrict__ x1,
    const float* __restrict__ ML, int i0, int i1, int nb,
    const float* __restrict__ xself,
    const ushort_t* __restrict__ Bh, const ushort_t* __restrict__ Bl,
    const float* __restrict__ fb,
    float* __restrict__ T, int N)
{
    const int lane = threadIdx.x & 63;
    const int l15  = lane & 15, lg = lane >> 4;
    const int wv   = threadIdx.x >> 6;
    const int r0   = blockIdx.x * 64 + wv * 16;

    const float M0 = ML[i0 * 2], rL0 = 1.0f / ML[i0 * 2 + 1];
    const float M1 = ML[i1 * 2], rL1 = 1.0f / ML[i1 * 2 + 1];

    for (int s = 0; s < 4; ++s) {
        const int row = r0 + s * 4 + lg;
        if (row < N) {
            float a8[8];
            *(float4*)(a8 + 0) = *(const float4*)&xself[(size_t)row * 128 + l15 * 8];
            *(float4*)(a8 + 4) = *(const float4*)&xself[(size_t)row * 128 + l15 * 8 + 4];

#pragma unroll
            for (int bsel = 0; bsel < 2; ++bsel) {
                if (bsel >= nb) break;
                const int* cn = bsel ? cnt1 : cnt0;
                const uint_t* bk = bsel ? bkt1 : bkt0;
                const ushort_t* xs = bsel ? x1 : x0;
                const float M = bsel ? M1 : M0;
                const float rL = bsel ? rL1 : rL0;

                int c = cn[row]; if (c > BKT_CAP) c = BKT_CAP;
                const uint_t* b = &bk[(size_t)row * BKT_CAP];
                int e = 0;
                for (; e + 3 < c; e += 4) {
                    uint_t v[4];
#pragma unroll
                    for (int k = 0; k < 4; ++k) v[k] = b[e + k];
                    uint4 f[4];
#pragma unroll
                    for (int k = 0; k < 4; ++k)
                        f[k] = *(const uint4*)&xs[(size_t)(v[k] & 0xFFFF) * 128 + l15 * 8];
#pragma unroll
                    for (int k = 0; k < 4; ++k) {
                        const float al = __expf(f16f((ushort_t)(v[k] >> 16)) - M) * rL;
                        const __half2* hp = (const __half2*)&f[k];
#pragma unroll
                        for (int j = 0; j < 4; ++j) {
                            const float2 vf = __half22float2(hp[j]);
                            a8[2 * j]     = fmaf(-al, vf.x, a8[2 * j]);
                            a8[2 * j + 1] = fmaf(-al, vf.y, a8[2 * j + 1]);
                        }
                    }
                }
                for (; e < c; ++e) {
                    const uint_t v = b[e];
                    const uint4 f0 = *(const uint4*)&xs[(size_t)(v & 0xFFFF) * 128 + l15 * 8];
                    const float al = __expf(f16f((ushort_t)(v >> 16)) - M) * rL;
                    const __half2* hp = (const __half2*)&f0;
#pragma unroll
                    for (int j = 0; j < 4; ++j) {
                        const float2 vf = __half22float2(hp[j]);
                        a8[2 * j]     = fmaf(-al, vf.x, a8[2 * j]);
                        a8[2 * j + 1] = fmaf(-al, vf.y, a8[2 * j + 1]);
                    }
                }
            }
            *(float4*)&T[(size_t)row * 128 + l15 * 8]     = *(float4*)(a8 + 0);
            *(float4*)&T[(size_t)row * 128 + l15 * 8 + 4] = *(float4*)(a8 + 4);
        }
    }
    __syncthreads();

    // ---- Phase 2: final MFMA on rows [r0, r0+16)
    const int arow = (r0 + l15 < N) ? (r0 + l15) : (N - 1);
    bf16x8 ahi[4], alo[4];
#pragma unroll
    for (int kt = 0; kt < 4; ++kt) {
        float v[8];
        *(float4*)(v + 0) = *(const float4*)&T[(size_t)arow * 128 + kt * 32 + lg * 8];
        *(float4*)(v + 4) = *(const float4*)&T[(size_t)arow * 128 + kt * 32 + lg * 8 + 4];
#pragma unroll
        for (int j = 0; j < 8; ++j) {
            const ushort_t h = bf16r(v[j]);
            ahi[kt][j] = (short)h;
            alo[kt][j] = (short)bf16r(v[j] - bf2f(h));
        }
    }

    f32x4 acc[8];
#pragma unroll
    for (int ct = 0; ct < 8; ++ct) {
        const float b = fb[ct * 16 + l15];
#pragma unroll
        for (int i = 0; i < 4; ++i) {
            const int row = r0 + lg * 4 + i;
            const int rr = (row < N) ? row : (N - 1);
            acc[ct][i] = T[(size_t)rr * 128 + ct * 16 + l15] + b;
        }
    }

#pragma unroll
    for (int ct = 0; ct < 8; ++ct) {
#pragma unroll
        for (int kt = 0; kt < 4; ++kt) {
            const size_t fo = (size_t)((ct * 4 + kt) * 64 + lane) * 8;
            const bf16x8 bhf = *(const bf16x8*)&Bh[fo];
            const bf16x8 blf = *(const bf16x8*)&Bl[fo];
            acc[ct] = __builtin_amdgcn_mfma_f32_16x16x32_bf16(ahi[kt], bhf, acc[ct], 0, 0, 0);
            acc[ct] = __builtin_amdgcn_mfma_f32_16x16x32_bf16(alo[kt], bhf, acc[ct], 0, 0, 0);
            acc[ct] = __builtin_amdgcn_mfma_f32_16x16x32_bf16(ahi[kt], blf, acc[ct], 0, 0, 0);
        }
    }
#pragma unroll
    for (int ct = 0; ct < 8; ++ct) {
#pragma unroll
        for (int i = 0; i < 4; ++i) {
            const int row = r0 + lg * 4 + i;
            if (row < N) T[(size_t)row * 128 + ct * 16 + l15] = acc[ct][i];
        }
    }
}

// ---------------------------------------------------------------------------
extern "C" void kernel_launch(void* const* d_in, const int* in_sizes, int n_in,
                              void* d_out, int out_size, void* d_ws, size_t ws_size,
                              hipStream_t stream)
{
    const float* x_a   = (const float*)d_in[0];
    const float* x_b   = (const float*)d_in[1];
    const int*   ei_ab = (const int*)d_in[2];
    const float* ea_ab = (const float*)d_in[3];
    const int*   ei_aa = (const int*)d_in[4];
    const float* ea_aa = (const float*)d_in[5];
    const float* Wh_w  = (const float*)d_in[6];
    const float* Wh_b  = (const float*)d_in[7];
    const float* Wn_w  = (const float*)d_in[8];
    const float* Wn_b  = (const float*)d_in[9];
    const float* w_e   = (const float*)d_in[10];
    const float* ft_w  = (const float*)d_in[11];
    const float* ft_b  = (const float*)d_in[12];

    float* out = (float*)d_out;
    float* ws  = (float*)d_ws;

    // ws layout (float offsets; all regions disjoint; peak ~20.5M floats)
    ushort_t* P1h  = (ushort_t*)(ws);              // 6.4M ushorts
    ushort_t* P2ah = (ushort_t*)(ws + 3200000);
    ushort_t* P2bh = (ushort_t*)(ws + 6400000);
    ushort_t* xa16 = (ushort_t*)(ws + 9600000);
    ushort_t* xb16 = (ushort_t*)(ws + 12800000);
    int* cntAab = (int*)(ws + 16000000);           // 3x50000 contiguous
    int* cntAaa = (int*)(ws + 16050000);
    int* cntB   = (int*)(ws + 16100000);
    float* pm  = ws + 16150000;                    // 40000 (20000 per type)
    float* pl  = ws + 16190000;                    // 40000
    float* ML  = ws + 16230000;                    // 4
    float* wep = ws + 16230016;                    // 128
    ushort_t* FR = (ushort_t*)(ws + 16230208);     // 114688 ushorts
    ushort_t* BhWh = FR;
    ushort_t* BlWh = FR + 8192;
    ushort_t* BhW1 = FR + 16384;
    ushort_t* BlW1 = FR + 32768;
    ushort_t* BhW2 = FR + 49152;
    ushort_t* BlW2 = FR + 65536;
    ushort_t* BhFT = FR + 81920;
    ushort_t* BlFT = FR + 98304;                   // ends ws+16287552
    uint_t* bktAab = (uint_t*)(ws + 16290000);     // 50000*28 = 1.4M uints
    uint_t* bktAaa = (uint_t*)(ws + 17690000);
    uint_t* bktB   = (uint_t*)(ws + 19090000);     // ends 20490000

    // d_out layout: out_a[6.4M] out_b[6.4M] alpha_ab[320K] alpha_aa[320K]
    float* TA   = out;
    float* TB   = out + 6400000;
    float* alAB = out + 12800000;   // raw scores, then normalized in place
    float* alAA = out + 13120000;

    // 0) zero bucket counters; pack weights
    hipMemsetAsync(cntAab, 0, 150000 * sizeof(int), stream);
    prep_w_all<<<113, 64, 0, stream>>>(Wh_w, Wn_w, Wn_w + 128 * 128, ft_w, w_e,
                                       BhWh, BlWh, BhW1, BlW1, BhW2, BlW2, BhFT, BlFT, wep);

    // 1) node projections (f16 tables, interleaved layout) + f16 x copies
    proj_dual_mfma<<<(N_A + 63) / 64, 256, 0, stream>>>(x_a, BhW1, BlW1, BhW2, BlW2,
                                                        Wh_b, Wn_b, P1h, P2ah, xa16, N_A);
    proj_single_mfma<<<(N_B + 63) / 64, 256, 0, stream>>>(x_b, BhW2, BlW2, P2bh, xb16, N_B);

    // 2) merged edge scores + inline bucket-CSR + softmax wave partials
    edge_score_k<<<5000, 512, 0, stream>>>(ea_ab, ea_aa, ei_ab, ei_aa,
                                           P1h, P2ah, P2bh, BhWh, BlWh, wep,
                                           alAB, alAA,
                                           cntAab, cntAaa, cntB,
                                           bktAab, bktAaa, bktB, pm, pl);

    // 3) softmax final reduction + alpha normalization
    softmax_final_kernel<<<2, 1024, 0, stream>>>(pm, pl, ML, 20000);
    alpha_norm_kernel<<<(E_AB + 255) / 256, 256, 0, stream>>>(alAB, alAA, ML);

    // 4) fused gather + final transform (A: two buckets; B: one)
    gather_final<<<(N_A + 63) / 64, 256, 0, stream>>>(
        cntAab, bktAab, xb16,            // bucket0: AB edges -> source x_b, ML[0,1]
        cntAaa, bktAaa, xa16,            // bucket1: AA edges -> source x_a, ML[2,3]
        ML, 0, 1, 2,
        x_a, BhFT, BlFT, ft_b, TA, N_A);
    gather_final<<<(N_B + 63) / 64, 256, 0, stream>>>(
        cntB, bktB, xa16,                // bucket0: AB edges -> source x_a, ML[0,1]
        cntB, bktB, xa16,                // unused (nb=1)
        ML, 0, 0, 1,
        x_b, BhFT, BlFT, ft_b, TB, N_B);

    (void)in_sizes; (void)n_in; (void)out_size; (void)ws_size;
}

// Round 14
// 327.651 us; speedup vs baseline: 1.5951x; 1.0953x over previous
//
#include <hip/hip_runtime.h>
#include <hip/hip_fp16.h>
#include <cstdint>
#include <cstddef>

// Problem constants (fixed by the reference)
#define N_A   50000
#define N_B   50000
#define E_AB  320000
#define E_AA  320000
#define IN_DIM 128
#define HID    128
#define ED     64

using bf16x8 = __attribute__((ext_vector_type(8))) short;
using f32x4  = __attribute__((ext_vector_type(4))) float;
typedef unsigned short ushort_t;
typedef unsigned int   uint_t;

__device__ inline ushort_t bf16r(float f) {   // f32 -> bf16 bits, RNE
    uint_t u = __float_as_uint(f);
    u = (u + 0x7FFF + ((u >> 16) & 1)) >> 16;
    return (ushort_t)u;
}
__device__ inline float bf2f(ushort_t h) {
    return __uint_as_float(((uint_t)h) << 16);
}
__device__ inline ushort_t f16r(float f) { return __half_as_ushort(__float2half_rn(f)); }
__device__ inline float f16f(ushort_t u) { return __half2float(__ushort_as_half(u)); }
__device__ inline uint_t packh2(float a, float b) {
    return (uint_t)f16r(a) | ((uint_t)f16r(b) << 16);
}

// 4B CSR entry: bits[15:0]=src row, bit16=flag, bits[31:17]=f16(score)>>1
__device__ inline uint_t enc_entry(int src, int flag, float score) {
    const uint_t h = (uint_t)f16r(score);
    return (uint_t)src | ((uint_t)flag << 16) | ((h & 0xFFFEu) << 16);
}

__device__ inline void online_merge(float& m, float& l, float om, float ol) {
    const float nm = fmaxf(m, om);
    l = l * __expf(m - nm) + ol * __expf(om - nm);
    m = nm;
}

// ---------------------------------------------------------------------------
// Pre-pack all weights into bf16 hi/lo MFMA B-fragments + permuted w_e.
// ---------------------------------------------------------------------------
__global__ __launch_bounds__(64) void prep_w_all(
    const float* __restrict__ Wh, const float* __restrict__ W1,
    const float* __restrict__ W2, const float* __restrict__ FT,
    const float* __restrict__ we,
    ushort_t* __restrict__ BhWh, ushort_t* __restrict__ BlWh,
    ushort_t* __restrict__ BhW1, ushort_t* __restrict__ BlW1,
    ushort_t* __restrict__ BhW2, ushort_t* __restrict__ BlW2,
    ushort_t* __restrict__ BhFT, ushort_t* __restrict__ BlFT,
    float* __restrict__ wep)
{
    const int f = blockIdx.x;
    const int lane = threadIdx.x;
    if (f == 112) {
#pragma unroll
        for (int q = 0; q < 2; ++q) {
            const int idx = lane + q * 64;
            const int l15 = idx >> 3, ct = idx & 7;
            wep[idx] = we[ct * 16 + l15];
        }
        return;
    }
    const float* W; ushort_t *oh, *ol; int KT, fl;
    if (f < 16)      { W = Wh; oh = BhWh; ol = BlWh; KT = 2; fl = f; }
    else if (f < 48) { W = W1; oh = BhW1; ol = BlW1; KT = 4; fl = f - 16; }
    else if (f < 80) { W = W2; oh = BhW2; ol = BlW2; KT = 4; fl = f - 48; }
    else             { W = FT; oh = BhFT; ol = BlFT; KT = 4; fl = f - 80; }
    const int ct = fl / KT, kt = fl % KT;
    const int col = ct * 16 + (lane & 15);
    const int kb  = kt * 32 + (lane >> 4) * 8;
#pragma unroll
    for (int j = 0; j < 8; ++j) {
        const float v = W[(kb + j) * 128 + col];
        const ushort_t h = bf16r(v);
        oh[(size_t)(fl * 64 + lane) * 8 + j] = h;
        ol[(size_t)(fl * 64 + lane) * 8 + j] = bf16r(v - bf2f(h));
    }
}

// ---------------------------------------------------------------------------
// proj_dual: P1 = x_a@W1 + (bh+bn), P2 = x_a@W2, f16 interleaved; emits xa16.
// ---------------------------------------------------------------------------
__global__ __launch_bounds__(256) void proj_dual_mfma(
    const float* __restrict__ X,
    const ushort_t* __restrict__ B1h, const ushort_t* __restrict__ B1l,
    const ushort_t* __restrict__ B2h, const ushort_t* __restrict__ B2l,
    const float* __restrict__ bh, const float* __restrict__ bn,
    ushort_t* __restrict__ P1, ushort_t* __restrict__ P2,
    ushort_t* __restrict__ X16, int N)
{
    const int lane = threadIdx.x & 63;
    const int l15 = lane & 15, lg = lane >> 4;
    const int r0 = blockIdx.x * 64 + (threadIdx.x >> 6) * 16;
    const int arow = (r0 + l15 < N) ? (r0 + l15) : (N - 1);

    bf16x8 ahi[4], alo[4];
#pragma unroll
    for (int kt = 0; kt < 4; ++kt) {
        float v[8];
        *(float4*)(v + 0) = *(const float4*)&X[(size_t)arow * 128 + kt * 32 + lg * 8];
        *(float4*)(v + 4) = *(const float4*)&X[(size_t)arow * 128 + kt * 32 + lg * 8 + 4];
        uint4 xu;
        xu.x = packh2(v[0], v[1]); xu.y = packh2(v[2], v[3]);
        xu.z = packh2(v[4], v[5]); xu.w = packh2(v[6], v[7]);
        *(uint4*)&X16[(size_t)arow * 128 + kt * 32 + lg * 8] = xu;
#pragma unroll
        for (int j = 0; j < 8; ++j) {
            const ushort_t h = bf16r(v[j]);
            ahi[kt][j] = (short)h;
            alo[kt][j] = (short)bf16r(v[j] - bf2f(h));
        }
    }

    f32x4 acc1[8], acc2[8];
#pragma unroll
    for (int ct = 0; ct < 8; ++ct) {
        const float b = bh[ct * 16 + l15] + bn[ct * 16 + l15];
        acc1[ct] = (f32x4){b, b, b, b};
        acc2[ct] = (f32x4){0.f, 0.f, 0.f, 0.f};
    }

#pragma unroll
    for (int ct = 0; ct < 8; ++ct) {
#pragma unroll
        for (int kt = 0; kt < 4; ++kt) {
            const size_t fo = (size_t)((ct * 4 + kt) * 64 + lane) * 8;
            const bf16x8 b1h = *(const bf16x8*)&B1h[fo];
            const bf16x8 b1l = *(const bf16x8*)&B1l[fo];
            const bf16x8 b2h = *(const bf16x8*)&B2h[fo];
            const bf16x8 b2l = *(const bf16x8*)&B2l[fo];
            acc1[ct] = __builtin_amdgcn_mfma_f32_16x16x32_bf16(ahi[kt], b1h, acc1[ct], 0, 0, 0);
            acc1[ct] = __builtin_amdgcn_mfma_f32_16x16x32_bf16(alo[kt], b1h, acc1[ct], 0, 0, 0);
            acc1[ct] = __builtin_amdgcn_mfma_f32_16x16x32_bf16(ahi[kt], b1l, acc1[ct], 0, 0, 0);
            acc2[ct] = __builtin_amdgcn_mfma_f32_16x16x32_bf16(ahi[kt], b2h, acc2[ct], 0, 0, 0);
            acc2[ct] = __builtin_amdgcn_mfma_f32_16x16x32_bf16(alo[kt], b2h, acc2[ct], 0, 0, 0);
            acc2[ct] = __builtin_amdgcn_mfma_f32_16x16x32_bf16(ahi[kt], b2l, acc2[ct], 0, 0, 0);
        }
    }
#pragma unroll
    for (int i = 0; i < 4; ++i) {
        const int row = r0 + lg * 4 + i;
        if (row < N) {
            uint4 u1, u2;
            u1.x = packh2(acc1[0][i], acc1[1][i]); u1.y = packh2(acc1[2][i], acc1[3][i]);
            u1.z = packh2(acc1[4][i], acc1[5][i]); u1.w = packh2(acc1[6][i], acc1[7][i]);
            u2.x = packh2(acc2[0][i], acc2[1][i]); u2.y = packh2(acc2[2][i], acc2[3][i]);
            u2.z = packh2(acc2[4][i], acc2[5][i]); u2.w = packh2(acc2[6][i], acc2[7][i]);
            *(uint4*)&P1[(size_t)row * 128 + l15 * 8] = u1;
            *(uint4*)&P2[(size_t)row * 128 + l15 * 8] = u2;
        }
    }
}

// proj_single: P = x_b@W2 (no bias), f16 interleaved; emits xb16.
__global__ __launch_bounds__(256) void proj_single_mfma(
    const float* __restrict__ X,
    const ushort_t* __restrict__ Bh, const ushort_t* __restrict__ Bl,
    ushort_t* __restrict__ P, ushort_t* __restrict__ X16, int N)
{
    const int lane = threadIdx.x & 63;
    const int l15 = lane & 15, lg = lane >> 4;
    const int r0 = blockIdx.x * 64 + (threadIdx.x >> 6) * 16;
    const int arow = (r0 + l15 < N) ? (r0 + l15) : (N - 1);

    bf16x8 ahi[4], alo[4];
#pragma unroll
    for (int kt = 0; kt < 4; ++kt) {
        float v[8];
        *(float4*)(v + 0) = *(const float4*)&X[(size_t)arow * 128 + kt * 32 + lg * 8];
        *(float4*)(v + 4) = *(const float4*)&X[(size_t)arow * 128 + kt * 32 + lg * 8 + 4];
        uint4 xu;
        xu.x = packh2(v[0], v[1]); xu.y = packh2(v[2], v[3]);
        xu.z = packh2(v[4], v[5]); xu.w = packh2(v[6], v[7]);
        *(uint4*)&X16[(size_t)arow * 128 + kt * 32 + lg * 8] = xu;
#pragma unroll
        for (int j = 0; j < 8; ++j) {
            const ushort_t h = bf16r(v[j]);
            ahi[kt][j] = (short)h;
            alo[kt][j] = (short)bf16r(v[j] - bf2f(h));
        }
    }

    f32x4 acc[8];
#pragma unroll
    for (int ct = 0; ct < 8; ++ct) acc[ct] = (f32x4){0.f, 0.f, 0.f, 0.f};

#pragma unroll
    for (int ct = 0; ct < 8; ++ct) {
#pragma unroll
        for (int kt = 0; kt < 4; ++kt) {
            const size_t fo = (size_t)((ct * 4 + kt) * 64 + lane) * 8;
            const bf16x8 bhf = *(const bf16x8*)&Bh[fo];
            const bf16x8 blf = *(const bf16x8*)&Bl[fo];
            acc[ct] = __builtin_amdgcn_mfma_f32_16x16x32_bf16(ahi[kt], bhf, acc[ct], 0, 0, 0);
            acc[ct] = __builtin_amdgcn_mfma_f32_16x16x32_bf16(alo[kt], bhf, acc[ct], 0, 0, 0);
            acc[ct] = __builtin_amdgcn_mfma_f32_16x16x32_bf16(ahi[kt], blf, acc[ct], 0, 0, 0);
        }
    }
#pragma unroll
    for (int i = 0; i < 4; ++i) {
        const int row = r0 + lg * 4 + i;
        if (row < N) {
            uint4 u;
            u.x = packh2(acc[0][i], acc[1][i]); u.y = packh2(acc[2][i], acc[3][i]);
            u.z = packh2(acc[4][i], acc[5][i]); u.w = packh2(acc[6][i], acc[7][i]);
            *(uint4*)&P[(size_t)row * 128 + l15 * 8] = u;
        }
    }
}

// ---------------------------------------------------------------------------
// Merged edge-score kernel — ROUND-9 EXACT BODY (the measured local optimum):
// 512-thread blocks, both B halves in 32 KB LDS, CSR count+rank at top,
// hoisted P gathers, block-level softmax partial with trailing barrier.
// grid 5000: blocks [0,2500) -> AB (128 edges), [2500,5000) -> AA.
// ---------------------------------------------------------------------------
__global__ __launch_bounds__(512) void edge_score_k(
    const float* __restrict__ ea_ab, const float* __restrict__ ea_aa,
    const int*   __restrict__ ei_ab, const int*   __restrict__ ei_aa,
    const ushort_t* __restrict__ P1h,
    const ushort_t* __restrict__ P2ah, const ushort_t* __restrict__ P2bh,
    const ushort_t* __restrict__ Bhi,  const ushort_t* __restrict__ Blo,
    const float* __restrict__ wep,
    float* __restrict__ scAB, float* __restrict__ scAA,
    int* __restrict__ cntA, int* __restrict__ cntB,
    int* __restrict__ rkAab, int* __restrict__ rkBab, int* __restrict__ rkAaa,
    float* __restrict__ pm, float* __restrict__ pl)
{
    const int t    = threadIdx.x;
    const int lane = t & 63;
    const int l15  = lane & 15;
    const int lg   = lane >> 4;
    const int wv   = t >> 6;                        // 0..7
    const int type = (blockIdx.x >= 2500);
    const int bb   = type ? (blockIdx.x - 2500) : blockIdx.x;
    const int eb   = bb * 128;

    const float* __restrict__ ea  = type ? ea_aa : ea_ab;
    const int*   __restrict__ ei  = type ? ei_aa : ei_ab;
    const ushort_t* __restrict__ P2h = type ? P2ah : P2bh;
    float* __restrict__ score = type ? scAA : scAB;

    __shared__ ushort_t sBh[8192];   // 16 KB
    __shared__ ushort_t sBl[8192];   // 16 KB
    {
        const uint4* gh = (const uint4*)Bhi;   // 1024 uint4 each
        const uint4* gl = (const uint4*)Blo;
        uint4* sh = (uint4*)sBh;
        uint4* sl = (uint4*)sBl;
#pragma unroll
        for (int i = 0; i < 2; ++i) {
            sh[t + i * 512] = gh[t + i * 512];
            sl[t + i * 512] = gl[t + i * 512];
        }
    }

    // fused CSR count + rank (threads 0..127 src side, 128..255 dst side)
    if (t < 128) {
        const int e = eb + t;
        const int s = ei[e];
        const int r = atomicAdd(&cntA[s], 1);
        if (type) rkAaa[e] = r; else rkAab[e] = r;
    } else if (t < 256 && !type) {
        const int e = eb + (t - 128);
        const int d = ei[(size_t)E_AB + e];
        rkBab[e] = atomicAdd(&cntB[d], 1);
    }

    const int e0 = eb + wv * 16;   // this wave's 16 edges

    // hoisted indices + P gathers (fly under A-conversion + MFMA)
    const int4 sv = *(const int4*)&ei[e0 + lg * 4];
    const int4 dv = *(const int4*)&ei[(size_t)E_AB + e0 + lg * 4];
    const int sidx[4] = {sv.x, sv.y, sv.z, sv.w};
    const int didx[4] = {dv.x, dv.y, dv.z, dv.w};
    uint4 p1u[4], p2u[4];
#pragma unroll
    for (int i = 0; i < 4; ++i) {
        p1u[i] = *(const uint4*)&P1h[(size_t)sidx[i] * 128 + l15 * 8];
        p2u[i] = *(const uint4*)&P2h[(size_t)didx[i] * 128 + l15 * 8];
    }

    // A fragment: row = l15 (edge e0+l15), k = kt*32 + lg*8 + j
    const float* arow = &ea[(size_t)(e0 + l15) * 64 + lg * 8];
    float af[16];
    *(float4*)(af + 0)  = *(const float4*)(arow + 0);
    *(float4*)(af + 4)  = *(const float4*)(arow + 4);
    *(float4*)(af + 8)  = *(const float4*)(arow + 32);
    *(float4*)(af + 12) = *(const float4*)(arow + 36);

    bf16x8 ahi0, alo0, ahi1, alo1;
#pragma unroll
    for (int j = 0; j < 8; ++j) {
        const ushort_t h0 = bf16r(af[j]);
        ahi0[j] = (short)h0;
        alo0[j] = (short)bf16r(af[j] - bf2f(h0));
        const ushort_t h1 = bf16r(af[8 + j]);
        ahi1[j] = (short)h1;
        alo1[j] = (short)bf16r(af[8 + j] - bf2f(h1));
    }

    __syncthreads();   // staging complete

    f32x4 acc[8];
#pragma unroll
    for (int ct = 0; ct < 8; ++ct) acc[ct] = (f32x4){0.f, 0.f, 0.f, 0.f};

#pragma unroll
    for (int ct = 0; ct < 8; ++ct) {
        const bf16x8 bh0 = *(const bf16x8*)&sBh[(ct * 2 + 0) * 512 + lane * 8];
        const bf16x8 bl0 = *(const bf16x8*)&sBl[(ct * 2 + 0) * 512 + lane * 8];
        const bf16x8 bh1 = *(const bf16x8*)&sBh[(ct * 2 + 1) * 512 + lane * 8];
        const bf16x8 bl1 = *(const bf16x8*)&sBl[(ct * 2 + 1) * 512 + lane * 8];
        acc[ct] = __builtin_amdgcn_mfma_f32_16x16x32_bf16(ahi0, bh0, acc[ct], 0, 0, 0);
        acc[ct] = __builtin_amdgcn_mfma_f32_16x16x32_bf16(alo0, bh0, acc[ct], 0, 0, 0);
        acc[ct] = __builtin_amdgcn_mfma_f32_16x16x32_bf16(ahi0, bl0, acc[ct], 0, 0, 0);
        acc[ct] = __builtin_amdgcn_mfma_f32_16x16x32_bf16(ahi1, bh1, acc[ct], 0, 0, 0);
        acc[ct] = __builtin_amdgcn_mfma_f32_16x16x32_bf16(alo1, bh1, acc[ct], 0, 0, 0);
        acc[ct] = __builtin_amdgcn_mfma_f32_16x16x32_bf16(ahi1, bl1, acc[ct], 0, 0, 0);
    }

    float w8[8];
    *(float4*)(w8 + 0) = *(const float4*)&wep[l15 * 8];
    *(float4*)(w8 + 4) = *(const float4*)&wep[l15 * 8 + 4];

    float part[4];
#pragma unroll
    for (int i = 0; i < 4; ++i) {
        const __half2* h1 = (const __half2*)&p1u[i];
        const __half2* h2 = (const __half2*)&p2u[i];
        float p = 0.f;
#pragma unroll
        for (int q = 0; q < 4; ++q) {
            const float2 pf = __half22float2(__hadd2(h1[q], h2[q]));
            p = fmaf(fmaxf(acc[2 * q][i] + pf.x, 0.f), w8[2 * q], p);
            p = fmaf(fmaxf(acc[2 * q + 1][i] + pf.y, 0.f), w8[2 * q + 1], p);
        }
        part[i] = p;
    }
#pragma unroll
    for (int m = 8; m >= 1; m >>= 1) {
#pragma unroll
        for (int i = 0; i < 4; ++i) part[i] += __shfl_xor(part[i], m, 64);
    }
    if (l15 == 0) {
#pragma unroll
        for (int i = 0; i < 4; ++i) score[e0 + lg * 4 + i] = part[i];
    }

    // fused softmax partials over this wave's 16 scores
    float mw = fmaxf(fmaxf(part[0], part[1]), fmaxf(part[2], part[3]));
    float lw = __expf(part[0] - mw) + __expf(part[1] - mw)
             + __expf(part[2] - mw) + __expf(part[3] - mw);
#pragma unroll
    for (int off = 16; off <= 32; off <<= 1) {
        const float om = __shfl_xor(mw, off, 64);
        const float ol = __shfl_xor(lw, off, 64);
        online_merge(mw, lw, om, ol);
    }
    __shared__ float smm[8], sll[8];
    if (lane == 0) { smm[wv] = mw; sll[wv] = lw; }
    __syncthreads();
    if (t == 0) {
        float M = smm[0], L = sll[0];
        for (int i = 1; i < 8; ++i) online_merge(M, L, smm[i], sll[i]);
        pm[blockIdx.x] = M;
        pl[blockIdx.x] = L;
    }
}

// ---------------------------------------------------------------------------
// Final softmax reduction over block partials; grid 2 (type per block)
// ---------------------------------------------------------------------------
__global__ __launch_bounds__(1024) void softmax_final_kernel(
    const float* __restrict__ pm, const float* __restrict__ pl,
    float* __restrict__ ML, int nPart)
{
    const int type = blockIdx.x;
    const float* mi = pm + type * nPart;
    const float* li = pl + type * nPart;
    float m = -1e30f, l = 0.f;
    for (int i = threadIdx.x; i < nPart; i += 1024) online_merge(m, l, mi[i], li[i]);
#pragma unroll
    for (int off = 1; off < 64; off <<= 1) {
        const float om = __shfl_xor(m, off, 64);
        const float ol = __shfl_xor(l, off, 64);
        online_merge(m, l, om, ol);
    }
    __shared__ float smm[16], sll[16];
    const int w = threadIdx.x >> 6, lane = threadIdx.x & 63;
    if (lane == 0) { smm[w] = m; sll[w] = l; }
    __syncthreads();
    if (threadIdx.x == 0) {
        float M = smm[0], L = sll[0];
        for (int i = 1; i < 16; ++i) online_merge(M, L, smm[i], sll[i]);
        ML[type * 2]     = M;
        ML[type * 2 + 1] = L;
    }
}

// ---------------------------------------------------------------------------
// CSR scan
// ---------------------------------------------------------------------------
__global__ __launch_bounds__(1024) void csr_scan_kernel(
    const int* __restrict__ cntA, int* __restrict__ offA,
    const int* __restrict__ cntB, int* __restrict__ offB, int N)
{
    const int* cnt = (blockIdx.x == 0) ? cntA : cntB;
    int* off = (blockIdx.x == 0) ? offA : offB;

    __shared__ int warpsum[16];
    const int t = threadIdx.x, lane = t & 63, w = t >> 6;
    int carry = 0;

    for (int base = 0; base < N; base += 1024) {
        const int i = base + t;
        const int v = (i < N) ? cnt[i] : 0;
        int x = v;
#pragma unroll
        for (int d = 1; d < 64; d <<= 1) {
            const int y = __shfl_up(x, d, 64);
            if (lane >= d) x += y;
        }
        if (lane == 63) warpsum[w] = x;
        __syncthreads();
        if (w == 0 && lane < 16) {
            int s = warpsum[lane];
#pragma unroll
            for (int d = 1; d < 16; d <<= 1) {
                const int y = __shfl_up(s, d, 64);
                if (lane >= d) s += y;
            }
            warpsum[lane] = s;
        }
        __syncthreads();
        const int excl = (x - v) + ((w > 0) ? warpsum[w - 1] : 0) + carry;
        if (i < N) off[i] = excl;
        carry += warpsum[15];
        __syncthreads();
    }
    if (t == 0) off[N] = carry;
}

// Atomic-free fill, 4B entries, fused softmax normalization.
__global__ __launch_bounds__(256) void csr_fill_kernel(
    const int* __restrict__ ei_ab, const int* __restrict__ ei_aa,
    float* __restrict__ scAB, float* __restrict__ scAA,
    const float* __restrict__ ML,
    const int* __restrict__ offA, const int* __restrict__ offB,
    const int* __restrict__ rkAab, const int* __restrict__ rkBab,
    const int* __restrict__ rkAaa,
    uint_t* __restrict__ idxA, uint_t* __restrict__ idxB)
{
    const int i = blockIdx.x * 256 + threadIdx.x;
    const float Mab = ML[0], rLab = 1.0f / ML[1];
    const float Maa = ML[2], rLaa = 1.0f / ML[3];
    if (i < E_AB) {
        const float sraw = scAB[i];
        scAB[i] = __expf(sraw - Mab) * rLab;
        const int s = ei_ab[i], d = ei_ab[E_AB + i];
        int pA = offA[s] + rkAab[i]; if (pA > 2 * E_AB - 1) pA = 2 * E_AB - 1;
        int pB = offB[d] + rkBab[i]; if (pB > E_AB - 1) pB = E_AB - 1;
        idxA[pA] = enc_entry(d, 1, sraw);   // flag 1: AB edge, src in x_b
        idxB[pB] = enc_entry(s, 0, sraw);   // flag 0 (all AB for TB)
    }
    if (i < E_AA) {
        const float sraw = scAA[i];
        scAA[i] = __expf(sraw - Maa) * rLaa;
        const int s = ei_aa[i];
        const int daa = ei_aa[E_AA + i];
        int pA = offA[s] + rkAaa[i]; if (pA > 2 * E_AB - 1) pA = 2 * E_AB - 1;
        idxA[pA] = enc_entry(daa, 0, sraw); // flag 0: AA edge, src in x_a
    }
}

// ---------------------------------------------------------------------------
// Fused gather + final. 4B entries; alpha = exp(f16(score) - M[flag]) * rL.
// Phase 2: final MFMA (T <- T + T@FT + fb) on the same 16 rows (L2-hot).
// ---------------------------------------------------------------------------
__global__ __launch_bounds__(256) void gather_final(
    const int*  __restrict__ off, const uint_t* __restrict__ idx,
    const ushort_t* __restrict__ xf0, const ushort_t* __restrict__ xf1,
    const float* __restrict__ ML, int i0, int i1,
    const float* __restrict__ xself,
    const ushort_t* __restrict__ Bh, const ushort_t* __restrict__ Bl,
    const float* __restrict__ fb,
    float* __restrict__ T, int N)
{
    const int lane = threadIdx.x & 63;
    const int l15  = lane & 15, lg = lane >> 4;
    const int wv   = threadIdx.x >> 6;
    const int r0   = blockIdx.x * 64 + wv * 16;

    const float M0 = ML[i0 * 2], rL0 = 1.0f / ML[i0 * 2 + 1];
    const float M1 = ML[i1 * 2], rL1 = 1.0f / ML[i1 * 2 + 1];

    for (int s = 0; s < 4; ++s) {
        const int row = r0 + s * 4 + lg;
        if (row < N) {
            const int beg = off[row], end = off[row + 1];
            float a8[8];
            *(float4*)(a8 + 0) = *(const float4*)&xself[(size_t)row * 128 + l15 * 8];
            *(float4*)(a8 + 4) = *(const float4*)&xself[(size_t)row * 128 + l15 * 8 + 4];
            int e = beg;
            for (; e + 3 < end; e += 4) {
                uint_t v[4];
#pragma unroll
                for (int k = 0; k < 4; ++k) v[k] = idx[e + k];
                uint4 f[4];
#pragma unroll
                for (int k = 0; k < 4; ++k) {
                    const ushort_t* sp = (v[k] & 0x10000u) ? xf1 : xf0;
                    f[k] = *(const uint4*)&sp[(size_t)(v[k] & 0xFFFFu) * 128 + l15 * 8];
                }
#pragma unroll
                for (int k = 0; k < 4; ++k) {
                    const int fl = (v[k] >> 16) & 1;
                    const float sc = f16f((ushort_t)((v[k] >> 16) & 0xFFFEu));
                    const float al = __expf(sc - (fl ? M1 : M0)) * (fl ? rL1 : rL0);
                    const __half2* hp = (const __half2*)&f[k];
#pragma unroll
                    for (int j = 0; j < 4; ++j) {
                        const float2 vf = __half22float2(hp[j]);
                        a8[2 * j]     = fmaf(-al, vf.x, a8[2 * j]);
                        a8[2 * j + 1] = fmaf(-al, vf.y, a8[2 * j + 1]);
                    }
                }
            }
            for (; e < end; ++e) {
                const uint_t v = idx[e];
                const ushort_t* sp = (v & 0x10000u) ? xf1 : xf0;
                const uint4 f0 = *(const uint4*)&sp[(size_t)(v & 0xFFFFu) * 128 + l15 * 8];
                const int fl = (v >> 16) & 1;
                const float sc = f16f((ushort_t)((v >> 16) & 0xFFFEu));
                const float al = __expf(sc - (fl ? M1 : M0)) * (fl ? rL1 : rL0);
                const __half2* hp = (const __half2*)&f0;
#pragma unroll
                for (int j = 0; j < 4; ++j) {
                    const float2 vf = __half22float2(hp[j]);
                    a8[2 * j]     = fmaf(-al, vf.x, a8[2 * j]);
                    a8[2 * j + 1] = fmaf(-al, vf.y, a8[2 * j + 1]);
                }
            }
            *(float4*)&T[(size_t)row * 128 + l15 * 8]     = *(float4*)(a8 + 0);
            *(float4*)&T[(size_t)row * 128 + l15 * 8 + 4] = *(float4*)(a8 + 4);
        }
    }
    __syncthreads();

    const int arow = (r0 + l15 < N) ? (r0 + l15) : (N - 1);
    bf16x8 ahi[4], alo[4];
#pragma unroll
    for (int kt = 0; kt < 4; ++kt) {
        float v[8];
        *(float4*)(v + 0) = *(const float4*)&T[(size_t)arow * 128 + kt * 32 + lg * 8];
        *(float4*)(v + 4) = *(const float4*)&T[(size_t)arow * 128 + kt * 32 + lg * 8 + 4];
#pragma unroll
        for (int j = 0; j < 8; ++j) {
            const ushort_t h = bf16r(v[j]);
            ahi[kt][j] = (short)h;
            alo[kt][j] = (short)bf16r(v[j] - bf2f(h));
        }
    }

    f32x4 acc[8];
#pragma unroll
    for (int ct = 0; ct < 8; ++ct) {
        const float b = fb[ct * 16 + l15];
#pragma unroll
        for (int i = 0; i < 4; ++i) {
            const int row = r0 + lg * 4 + i;
            const int rr = (row < N) ? row : (N - 1);
            acc[ct][i] = T[(size_t)rr * 128 + ct * 16 + l15] + b;
        }
    }

#pragma unroll
    for (int ct = 0; ct < 8; ++ct) {
#pragma unroll
        for (int kt = 0; kt < 4; ++kt) {
            const size_t fo = (size_t)((ct * 4 + kt) * 64 + lane) * 8;
            const bf16x8 bhf = *(const bf16x8*)&Bh[fo];
            const bf16x8 blf = *(const bf16x8*)&Bl[fo];
            acc[ct] = __builtin_amdgcn_mfma_f32_16x16x32_bf16(ahi[kt], bhf, acc[ct], 0, 0, 0);
            acc[ct] = __builtin_amdgcn_mfma_f32_16x16x32_bf16(alo[kt], bhf, acc[ct], 0, 0, 0);
            acc[ct] = __builtin_amdgcn_mfma_f32_16x16x32_bf16(ahi[kt], blf, acc[ct], 0, 0, 0);
        }
    }
#pragma unroll
    for (int ct = 0; ct < 8; ++ct) {
#pragma unroll
        for (int i = 0; i < 4; ++i) {
            const int row = r0 + lg * 4 + i;
            if (row < N) T[(size_t)row * 128 + ct * 16 + l15] = acc[ct][i];
        }
    }
}

// ---------------------------------------------------------------------------
extern "C" void kernel_launch(void* const* d_in, const int* in_sizes, int n_in,
                              void* d_out, int out_size, void* d_ws, size_t ws_size,
                              hipStream_t stream)
{
    const float* x_a   = (const float*)d_in[0];
    const float* x_b   = (const float*)d_in[1];
    const int*   ei_ab = (const int*)d_in[2];
    const float* ea_ab = (const float*)d_in[3];
    const int*   ei_aa = (const int*)d_in[4];
    const float* ea_aa = (const float*)d_in[5];
    const float* Wh_w  = (const float*)d_in[6];
    const float* Wh_b  = (const float*)d_in[7];
    const float* Wn_w  = (const float*)d_in[8];
    const float* Wn_b  = (const float*)d_in[9];
    const float* w_e   = (const float*)d_in[10];
    const float* ft_w  = (const float*)d_in[11];
    const float* ft_b  = (const float*)d_in[12];

    float* out = (float*)d_out;
    float* ws  = (float*)d_ws;

    // ws layout (float offsets; all regions disjoint)
    ushort_t* P1h  = (ushort_t*)(ws);              // 6.4M ushorts
    ushort_t* P2ah = (ushort_t*)(ws + 3200000);
    ushort_t* P2bh = (ushort_t*)(ws + 6400000);
    ushort_t* xa16 = (ushort_t*)(ws + 9600000);
    ushort_t* xb16 = (ushort_t*)(ws + 12800000);
    int* rkAab = (int*)(ws + 16000000);
    int* rkBab = (int*)(ws + 16320000);
    int* rkAaa = (int*)(ws + 16640000);
    int* cntA  = (int*)(ws + 16960000);            // cntA+cntB contiguous
    int* cntB  = (int*)(ws + 17010000);
    int* offA  = (int*)(ws + 17060000);            // 50001
    int* offB  = (int*)(ws + 17110004);            // 50001
    float* pm  = ws + 17160008;                    // 5000 (2500 per type)
    float* pl  = ws + 17165008;                    // 5000
    float* ML  = ws + 17170008;                    // 4
    float* wep = ws + 17170016;                    // 128
    ushort_t* FR = (ushort_t*)(ws + 17170208);     // 114688 ushorts
    ushort_t* BhWh = FR;
    ushort_t* BlWh = FR + 8192;
    ushort_t* BhW1 = FR + 16384;
    ushort_t* BlW1 = FR + 32768;
    ushort_t* BhW2 = FR + 49152;
    ushort_t* BlW2 = FR + 65536;
    ushort_t* BhFT = FR + 81920;
    ushort_t* BlFT = FR + 98304;                   // ends ws+17227552
    uint_t* idxA = (uint_t*)(ws + 17230000);       // 640000 uints
    uint_t* idxB = (uint_t*)(ws + 17870000);       // 320000 uints -> 18190000

    // d_out layout: out_a[6.4M] out_b[6.4M] alpha_ab[320K] alpha_aa[320K]
    float* TA   = out;
    float* TB   = out + 6400000;
    float* alAB = out + 12800000;   // raw scores, then normalized in csr_fill
    float* alAA = out + 13120000;

    // 0) zero CSR counters; pack weights
    hipMemsetAsync(cntA, 0, 100000 * sizeof(int), stream);
    prep_w_all<<<113, 64, 0, stream>>>(Wh_w, Wn_w, Wn_w + 128 * 128, ft_w, w_e,
                                       BhWh, BlWh, BhW1, BlW1, BhW2, BlW2, BhFT, BlFT, wep);

    // 1) node projections (f16 tables, interleaved layout) + f16 x copies
    proj_dual_mfma<<<(N_A + 63) / 64, 256, 0, stream>>>(x_a, BhW1, BlW1, BhW2, BlW2,
                                                        Wh_b, Wn_b, P1h, P2ah, xa16, N_A);
    proj_single_mfma<<<(N_B + 63) / 64, 256, 0, stream>>>(x_b, BhW2, BlW2, P2bh, xb16, N_B);

    // 2) merged edge scores (round-9 body: fused CSR count+rank, softmax
    //    block partials)
    edge_score_k<<<5000, 512, 0, stream>>>(ea_ab, ea_aa, ei_ab, ei_aa,
                                           P1h, P2ah, P2bh, BhWh, BlWh, wep,
                                           alAB, alAA, cntA, cntB,
                                           rkAab, rkBab, rkAaa, pm, pl);

    // 3) softmax final reduction (both types)
    softmax_final_kernel<<<2, 1024, 0, stream>>>(pm, pl, ML, 2500);

    // 4) CSR scan + atomic-free fill (4B entries, fused normalization)
    csr_scan_kernel<<<2, 1024, 0, stream>>>(cntA, offA, cntB, offB, N_A);
    csr_fill_kernel<<<(E_AB + 255) / 256, 256, 0, stream>>>(ei_ab, ei_aa, alAB, alAA, ML,
                                                            offA, offB, rkAab, rkBab, rkAaa,
                                                            idxA, idxB);

    // 5) fused gather + final transform
    //    TA: flag0 = AA (src x_a, ML[2,3]), flag1 = AB (src x_b, ML[0,1])
    gather_final<<<(N_A + 63) / 64, 256, 0, stream>>>(offA, idxA, xa16, xb16,
                                                      ML, 1, 0,
                                                      x_a, BhFT, BlFT, ft_b, TA, N_A);
    //    TB: all flag0 = AB (src x_a, ML[0,1])
    gather_final<<<(N_B + 63) / 64, 256, 0, stream>>>(offB, idxB, xa16, xb16,
                                                      ML, 0, 0,
                                                      x_b, BhFT, BlFT, ft_b, TB, N_B);

    (void)in_sizes; (void)n_in; (void)out_size; (void)ws_size;
}

// Round 15
// 299.208 us; speedup vs baseline: 1.7467x; 1.0951x over previous
//
#include <hip/hip_runtime.h>
#include <hip/hip_fp16.h>
#include <cstdint>
#include <cstddef>

// Problem constants (fixed by the reference)
#define N_A   50000
#define N_B   50000
#define E_AB  320000
#define E_AA  320000
#define IN_DIM 128
#define HID    128
#define ED     64

using bf16x8 = __attribute__((ext_vector_type(8))) short;
using f32x4  = __attribute__((ext_vector_type(4))) float;
typedef unsigned short ushort_t;
typedef unsigned int   uint_t;

__device__ inline ushort_t bf16r(float f) {   // f32 -> bf16 bits, RNE
    uint_t u = __float_as_uint(f);
    u = (u + 0x7FFF + ((u >> 16) & 1)) >> 16;
    return (ushort_t)u;
}
__device__ inline float bf2f(ushort_t h) {
    return __uint_as_float(((uint_t)h) << 16);
}
__device__ inline ushort_t f16r(float f) { return __half_as_ushort(__float2half_rn(f)); }
__device__ inline float f16f(ushort_t u) { return __half2float(__ushort_as_half(u)); }
__device__ inline uint_t packh2(float a, float b) {
    return (uint_t)f16r(a) | ((uint_t)f16r(b) << 16);
}

// 4B CSR entry: bits[15:0]=src row, bit16=flag, bits[31:17]=f16(score)>>1
__device__ inline uint_t enc_entry(int src, int flag, float score) {
    const uint_t h = (uint_t)f16r(score);
    return (uint_t)src | ((uint_t)flag << 16) | ((h & 0xFFFEu) << 16);
}

__device__ inline void online_merge(float& m, float& l, float om, float ol) {
    const float nm = fmaxf(m, om);
    l = l * __expf(m - nm) + ol * __expf(om - nm);
    m = nm;
}

// ---------------------------------------------------------------------------
// Pre-pack all weights into bf16 hi/lo MFMA B-fragments + permuted w_e.
// ---------------------------------------------------------------------------
__global__ __launch_bounds__(64) void prep_w_all(
    const float* __restrict__ Wh, const float* __restrict__ W1,
    const float* __restrict__ W2, const float* __restrict__ FT,
    const float* __restrict__ we,
    ushort_t* __restrict__ BhWh, ushort_t* __restrict__ BlWh,
    ushort_t* __restrict__ BhW1, ushort_t* __restrict__ BlW1,
    ushort_t* __restrict__ BhW2, ushort_t* __restrict__ BlW2,
    ushort_t* __restrict__ BhFT, ushort_t* __restrict__ BlFT,
    float* __restrict__ wep)
{
    const int f = blockIdx.x;
    const int lane = threadIdx.x;
    if (f == 112) {
#pragma unroll
        for (int q = 0; q < 2; ++q) {
            const int idx = lane + q * 64;
            const int l15 = idx >> 3, ct = idx & 7;
            wep[idx] = we[ct * 16 + l15];
        }
        return;
    }
    const float* W; ushort_t *oh, *ol; int KT, fl;
    if (f < 16)      { W = Wh; oh = BhWh; ol = BlWh; KT = 2; fl = f; }
    else if (f < 48) { W = W1; oh = BhW1; ol = BlW1; KT = 4; fl = f - 16; }
    else if (f < 80) { W = W2; oh = BhW2; ol = BlW2; KT = 4; fl = f - 48; }
    else             { W = FT; oh = BhFT; ol = BlFT; KT = 4; fl = f - 80; }
    const int ct = fl / KT, kt = fl % KT;
    const int col = ct * 16 + (lane & 15);
    const int kb  = kt * 32 + (lane >> 4) * 8;
#pragma unroll
    for (int j = 0; j < 8; ++j) {
        const float v = W[(kb + j) * 128 + col];
        const ushort_t h = bf16r(v);
        oh[(size_t)(fl * 64 + lane) * 8 + j] = h;
        ol[(size_t)(fl * 64 + lane) * 8 + j] = bf16r(v - bf2f(h));
    }
}

// ---------------------------------------------------------------------------
// Merged projections: blocks [0,nblkA) -> dual (x_a: P1,P2a + xa16),
//                     blocks [nblkA,..) -> single (x_b: P2b + xb16).
// ---------------------------------------------------------------------------
__global__ __launch_bounds__(256) void proj_all_mfma(
    const float* __restrict__ x_a, const float* __restrict__ x_b,
    const ushort_t* __restrict__ B1h, const ushort_t* __restrict__ B1l,
    const ushort_t* __restrict__ B2h, const ushort_t* __restrict__ B2l,
    const float* __restrict__ bh, const float* __restrict__ bn,
    ushort_t* __restrict__ P1, ushort_t* __restrict__ P2a,
    ushort_t* __restrict__ P2b,
    ushort_t* __restrict__ xa16, ushort_t* __restrict__ xb16,
    int nblkA)
{
    const int lane = threadIdx.x & 63;
    const int l15 = lane & 15, lg = lane >> 4;
    const int isA = (blockIdx.x < nblkA);
    const int bb  = isA ? blockIdx.x : (blockIdx.x - nblkA);
    const int r0  = bb * 64 + (threadIdx.x >> 6) * 16;
    const int N   = isA ? N_A : N_B;
    const float* __restrict__ X = isA ? x_a : x_b;
    ushort_t* __restrict__ X16  = isA ? xa16 : xb16;
    const int arow = (r0 + l15 < N) ? (r0 + l15) : (N - 1);

    bf16x8 ahi[4], alo[4];
#pragma unroll
    for (int kt = 0; kt < 4; ++kt) {
        float v[8];
        *(float4*)(v + 0) = *(const float4*)&X[(size_t)arow * 128 + kt * 32 + lg * 8];
        *(float4*)(v + 4) = *(const float4*)&X[(size_t)arow * 128 + kt * 32 + lg * 8 + 4];
        uint4 xu;
        xu.x = packh2(v[0], v[1]); xu.y = packh2(v[2], v[3]);
        xu.z = packh2(v[4], v[5]); xu.w = packh2(v[6], v[7]);
        *(uint4*)&X16[(size_t)arow * 128 + kt * 32 + lg * 8] = xu;
#pragma unroll
        for (int j = 0; j < 8; ++j) {
            const ushort_t h = bf16r(v[j]);
            ahi[kt][j] = (short)h;
            alo[kt][j] = (short)bf16r(v[j] - bf2f(h));
        }
    }

    if (isA) {
        f32x4 acc1[8], acc2[8];
#pragma unroll
        for (int ct = 0; ct < 8; ++ct) {
            const float b = bh[ct * 16 + l15] + bn[ct * 16 + l15];
            acc1[ct] = (f32x4){b, b, b, b};
            acc2[ct] = (f32x4){0.f, 0.f, 0.f, 0.f};
        }
#pragma unroll
        for (int ct = 0; ct < 8; ++ct) {
#pragma unroll
            for (int kt = 0; kt < 4; ++kt) {
                const size_t fo = (size_t)((ct * 4 + kt) * 64 + lane) * 8;
                const bf16x8 b1h = *(const bf16x8*)&B1h[fo];
                const bf16x8 b1l = *(const bf16x8*)&B1l[fo];
                const bf16x8 b2h = *(const bf16x8*)&B2h[fo];
                const bf16x8 b2l = *(const bf16x8*)&B2l[fo];
                acc1[ct] = __builtin_amdgcn_mfma_f32_16x16x32_bf16(ahi[kt], b1h, acc1[ct], 0, 0, 0);
                acc1[ct] = __builtin_amdgcn_mfma_f32_16x16x32_bf16(alo[kt], b1h, acc1[ct], 0, 0, 0);
                acc1[ct] = __builtin_amdgcn_mfma_f32_16x16x32_bf16(ahi[kt], b1l, acc1[ct], 0, 0, 0);
                acc2[ct] = __builtin_amdgcn_mfma_f32_16x16x32_bf16(ahi[kt], b2h, acc2[ct], 0, 0, 0);
                acc2[ct] = __builtin_amdgcn_mfma_f32_16x16x32_bf16(alo[kt], b2h, acc2[ct], 0, 0, 0);
                acc2[ct] = __builtin_amdgcn_mfma_f32_16x16x32_bf16(ahi[kt], b2l, acc2[ct], 0, 0, 0);
            }
        }
#pragma unroll
        for (int i = 0; i < 4; ++i) {
            const int row = r0 + lg * 4 + i;
            if (row < N_A) {
                uint4 u1, u2;
                u1.x = packh2(acc1[0][i], acc1[1][i]); u1.y = packh2(acc1[2][i], acc1[3][i]);
                u1.z = packh2(acc1[4][i], acc1[5][i]); u1.w = packh2(acc1[6][i], acc1[7][i]);
                u2.x = packh2(acc2[0][i], acc2[1][i]); u2.y = packh2(acc2[2][i], acc2[3][i]);
                u2.z = packh2(acc2[4][i], acc2[5][i]); u2.w = packh2(acc2[6][i], acc2[7][i]);
                *(uint4*)&P1[(size_t)row * 128 + l15 * 8]  = u1;
                *(uint4*)&P2a[(size_t)row * 128 + l15 * 8] = u2;
            }
        }
    } else {
        f32x4 acc[8];
#pragma unroll
        for (int ct = 0; ct < 8; ++ct) acc[ct] = (f32x4){0.f, 0.f, 0.f, 0.f};
#pragma unroll
        for (int ct = 0; ct < 8; ++ct) {
#pragma unroll
            for (int kt = 0; kt < 4; ++kt) {
                const size_t fo = (size_t)((ct * 4 + kt) * 64 + lane) * 8;
                const bf16x8 bhf = *(const bf16x8*)&B2h[fo];
                const bf16x8 blf = *(const bf16x8*)&B2l[fo];
                acc[ct] = __builtin_amdgcn_mfma_f32_16x16x32_bf16(ahi[kt], bhf, acc[ct], 0, 0, 0);
                acc[ct] = __builtin_amdgcn_mfma_f32_16x16x32_bf16(alo[kt], bhf, acc[ct], 0, 0, 0);
                acc[ct] = __builtin_amdgcn_mfma_f32_16x16x32_bf16(ahi[kt], blf, acc[ct], 0, 0, 0);
            }
        }
#pragma unroll
        for (int i = 0; i < 4; ++i) {
            const int row = r0 + lg * 4 + i;
            if (row < N_B) {
                uint4 u;
                u.x = packh2(acc[0][i], acc[1][i]); u.y = packh2(acc[2][i], acc[3][i]);
                u.z = packh2(acc[4][i], acc[5][i]); u.w = packh2(acc[6][i], acc[7][i]);
                *(uint4*)&P2b[(size_t)row * 128 + l15 * 8] = u;
            }
        }
    }
}

// ---------------------------------------------------------------------------
// Merged edge-score kernel — round-9 exact body (measured local optimum).
// grid 5000: blocks [0,2500) -> AB (128 edges), [2500,5000) -> AA.
// ---------------------------------------------------------------------------
__global__ __launch_bounds__(512) void edge_score_k(
    const float* __restrict__ ea_ab, const float* __restrict__ ea_aa,
    const int*   __restrict__ ei_ab, const int*   __restrict__ ei_aa,
    const ushort_t* __restrict__ P1h,
    const ushort_t* __restrict__ P2ah, const ushort_t* __restrict__ P2bh,
    const ushort_t* __restrict__ Bhi,  const ushort_t* __restrict__ Blo,
    const float* __restrict__ wep,
    float* __restrict__ scAB, float* __restrict__ scAA,
    int* __restrict__ cntA, int* __restrict__ cntB,
    int* __restrict__ rkAab, int* __restrict__ rkBab, int* __restrict__ rkAaa,
    float* __restrict__ pm, float* __restrict__ pl)
{
    const int t    = threadIdx.x;
    const int lane = t & 63;
    const int l15  = lane & 15;
    const int lg   = lane >> 4;
    const int wv   = t >> 6;                        // 0..7
    const int type = (blockIdx.x >= 2500);
    const int bb   = type ? (blockIdx.x - 2500) : blockIdx.x;
    const int eb   = bb * 128;

    const float* __restrict__ ea  = type ? ea_aa : ea_ab;
    const int*   __restrict__ ei  = type ? ei_aa : ei_ab;
    const ushort_t* __restrict__ P2h = type ? P2ah : P2bh;
    float* __restrict__ score = type ? scAA : scAB;

    __shared__ ushort_t sBh[8192];   // 16 KB
    __shared__ ushort_t sBl[8192];   // 16 KB
    {
        const uint4* gh = (const uint4*)Bhi;   // 1024 uint4 each
        const uint4* gl = (const uint4*)Blo;
        uint4* sh = (uint4*)sBh;
        uint4* sl = (uint4*)sBl;
#pragma unroll
        for (int i = 0; i < 2; ++i) {
            sh[t + i * 512] = gh[t + i * 512];
            sl[t + i * 512] = gl[t + i * 512];
        }
    }

    // fused CSR count + rank (threads 0..127 src side, 128..255 dst side)
    if (t < 128) {
        const int e = eb + t;
        const int s = ei[e];
        const int r = atomicAdd(&cntA[s], 1);
        if (type) rkAaa[e] = r; else rkAab[e] = r;
    } else if (t < 256 && !type) {
        const int e = eb + (t - 128);
        const int d = ei[(size_t)E_AB + e];
        rkBab[e] = atomicAdd(&cntB[d], 1);
    }

    const int e0 = eb + wv * 16;   // this wave's 16 edges

    // hoisted indices + P gathers (fly under A-conversion + MFMA)
    const int4 sv = *(const int4*)&ei[e0 + lg * 4];
    const int4 dv = *(const int4*)&ei[(size_t)E_AB + e0 + lg * 4];
    const int sidx[4] = {sv.x, sv.y, sv.z, sv.w};
    const int didx[4] = {dv.x, dv.y, dv.z, dv.w};
    uint4 p1u[4], p2u[4];
#pragma unroll
    for (int i = 0; i < 4; ++i) {
        p1u[i] = *(const uint4*)&P1h[(size_t)sidx[i] * 128 + l15 * 8];
        p2u[i] = *(const uint4*)&P2h[(size_t)didx[i] * 128 + l15 * 8];
    }

    // A fragment: row = l15 (edge e0+l15), k = kt*32 + lg*8 + j
    const float* arow = &ea[(size_t)(e0 + l15) * 64 + lg * 8];
    float af[16];
    *(float4*)(af + 0)  = *(const float4*)(arow + 0);
    *(float4*)(af + 4)  = *(const float4*)(arow + 4);
    *(float4*)(af + 8)  = *(const float4*)(arow + 32);
    *(float4*)(af + 12) = *(const float4*)(arow + 36);

    bf16x8 ahi0, alo0, ahi1, alo1;
#pragma unroll
    for (int j = 0; j < 8; ++j) {
        const ushort_t h0 = bf16r(af[j]);
        ahi0[j] = (short)h0;
        alo0[j] = (short)bf16r(af[j] - bf2f(h0));
        const ushort_t h1 = bf16r(af[8 + j]);
        ahi1[j] = (short)h1;
        alo1[j] = (short)bf16r(af[8 + j] - bf2f(h1));
    }

    __syncthreads();   // staging complete

    f32x4 acc[8];
#pragma unroll
    for (int ct = 0; ct < 8; ++ct) acc[ct] = (f32x4){0.f, 0.f, 0.f, 0.f};

#pragma unroll
    for (int ct = 0; ct < 8; ++ct) {
        const bf16x8 bh0 = *(const bf16x8*)&sBh[(ct * 2 + 0) * 512 + lane * 8];
        const bf16x8 bl0 = *(const bf16x8*)&sBl[(ct * 2 + 0) * 512 + lane * 8];
        const bf16x8 bh1 = *(const bf16x8*)&sBh[(ct * 2 + 1) * 512 + lane * 8];
        const bf16x8 bl1 = *(const bf16x8*)&sBl[(ct * 2 + 1) * 512 + lane * 8];
        acc[ct] = __builtin_amdgcn_mfma_f32_16x16x32_bf16(ahi0, bh0, acc[ct], 0, 0, 0);
        acc[ct] = __builtin_amdgcn_mfma_f32_16x16x32_bf16(alo0, bh0, acc[ct], 0, 0, 0);
        acc[ct] = __builtin_amdgcn_mfma_f32_16x16x32_bf16(ahi0, bl0, acc[ct], 0, 0, 0);
        acc[ct] = __builtin_amdgcn_mfma_f32_16x16x32_bf16(ahi1, bh1, acc[ct], 0, 0, 0);
        acc[ct] = __builtin_amdgcn_mfma_f32_16x16x32_bf16(alo1, bh1, acc[ct], 0, 0, 0);
        acc[ct] = __builtin_amdgcn_mfma_f32_16x16x32_bf16(ahi1, bl1, acc[ct], 0, 0, 0);
    }

    float w8[8];
    *(float4*)(w8 + 0) = *(const float4*)&wep[l15 * 8];
    *(float4*)(w8 + 4) = *(const float4*)&wep[l15 * 8 + 4];

    float part[4];
#pragma unroll
    for (int i = 0; i < 4; ++i) {
        const __half2* h1 = (const __half2*)&p1u[i];
        const __half2* h2 = (const __half2*)&p2u[i];
        float p = 0.f;
#pragma unroll
        for (int q = 0; q < 4; ++q) {
            const float2 pf = __half22float2(__hadd2(h1[q], h2[q]));
            p = fmaf(fmaxf(acc[2 * q][i] + pf.x, 0.f), w8[2 * q], p);
            p = fmaf(fmaxf(acc[2 * q + 1][i] + pf.y, 0.f), w8[2 * q + 1], p);
        }
        part[i] = p;
    }
#pragma unroll
    for (int m = 8; m >= 1; m >>= 1) {
#pragma unroll
        for (int i = 0; i < 4; ++i) part[i] += __shfl_xor(part[i], m, 64);
    }
    if (l15 == 0) {
#pragma unroll
        for (int i = 0; i < 4; ++i) score[e0 + lg * 4 + i] = part[i];
    }

    // fused softmax partials over this wave's 16 scores
    float mw = fmaxf(fmaxf(part[0], part[1]), fmaxf(part[2], part[3]));
    float lw = __expf(part[0] - mw) + __expf(part[1] - mw)
             + __expf(part[2] - mw) + __expf(part[3] - mw);
#pragma unroll
    for (int off = 16; off <= 32; off <<= 1) {
        const float om = __shfl_xor(mw, off, 64);
        const float ol = __shfl_xor(lw, off, 64);
        online_merge(mw, lw, om, ol);
    }
    __shared__ float smm[8], sll[8];
    if (lane == 0) { smm[wv] = mw; sll[wv] = lw; }
    __syncthreads();
    if (t == 0) {
        float M = smm[0], L = sll[0];
        for (int i = 1; i < 8; ++i) online_merge(M, L, smm[i], sll[i]);
        pm[blockIdx.x] = M;
        pl[blockIdx.x] = L;
    }
}

// ---------------------------------------------------------------------------
// Merged softmax-final + CSR-scan: blocks 0,1 reduce pm/pl per type -> ML;
// blocks 2,3 exclusive-scan cntA/cntB -> offA/offB. All independent.
// ---------------------------------------------------------------------------
__global__ __launch_bounds__(1024) void softmax_scan_kernel(
    const float* __restrict__ pm, const float* __restrict__ pl,
    float* __restrict__ ML, int nPart,
    const int* __restrict__ cntA, int* __restrict__ offA,
    const int* __restrict__ cntB, int* __restrict__ offB, int N)
{
    const int t = threadIdx.x, lane = t & 63, w = t >> 6;

    if (blockIdx.x < 2) {
        const int type = blockIdx.x;
        const float* mi = pm + type * nPart;
        const float* li = pl + type * nPart;
        float m = -1e30f, l = 0.f;
        for (int i = t; i < nPart; i += 1024) online_merge(m, l, mi[i], li[i]);
#pragma unroll
        for (int off = 1; off < 64; off <<= 1) {
            const float om = __shfl_xor(m, off, 64);
            const float ol = __shfl_xor(l, off, 64);
            online_merge(m, l, om, ol);
        }
        __shared__ float smm[16], sll[16];
        if (lane == 0) { smm[w] = m; sll[w] = l; }
        __syncthreads();
        if (t == 0) {
            float M = smm[0], L = sll[0];
            for (int i = 1; i < 16; ++i) online_merge(M, L, smm[i], sll[i]);
            ML[type * 2]     = M;
            ML[type * 2 + 1] = L;
        }
    } else {
        const int* cnt = (blockIdx.x == 2) ? cntA : cntB;
        int* off = (blockIdx.x == 2) ? offA : offB;

        __shared__ int warpsum[16];
        int carry = 0;
        for (int base = 0; base < N; base += 1024) {
            const int i = base + t;
            const int v = (i < N) ? cnt[i] : 0;
            int x = v;
#pragma unroll
            for (int d = 1; d < 64; d <<= 1) {
                const int y = __shfl_up(x, d, 64);
                if (lane >= d) x += y;
            }
            if (lane == 63) warpsum[w] = x;
            __syncthreads();
            if (w == 0 && lane < 16) {
                int s = warpsum[lane];
#pragma unroll
                for (int d = 1; d < 16; d <<= 1) {
                    const int y = __shfl_up(s, d, 64);
                    if (lane >= d) s += y;
                }
                warpsum[lane] = s;
            }
            __syncthreads();
            const int excl = (x - v) + ((w > 0) ? warpsum[w - 1] : 0) + carry;
            if (i < N) off[i] = excl;
            carry += warpsum[15];
            __syncthreads();
        }
        if (t == 0) off[N] = carry;
    }
}

// Atomic-free fill, 4B entries, fused softmax normalization.
__global__ __launch_bounds__(256) void csr_fill_kernel(
    const int* __restrict__ ei_ab, const int* __restrict__ ei_aa,
    float* __restrict__ scAB, float* __restrict__ scAA,
    const float* __restrict__ ML,
    const int* __restrict__ offA, const int* __restrict__ offB,
    const int* __restrict__ rkAab, const int* __restrict__ rkBab,
    const int* __restrict__ rkAaa,
    uint_t* __restrict__ idxA, uint_t* __restrict__ idxB)
{
    const int i = blockIdx.x * 256 + threadIdx.x;
    const float Mab = ML[0], rLab = 1.0f / ML[1];
    const float Maa = ML[2], rLaa = 1.0f / ML[3];
    if (i < E_AB) {
        const float sraw = scAB[i];
        scAB[i] = __expf(sraw - Mab) * rLab;
        const int s = ei_ab[i], d = ei_ab[E_AB + i];
        int pA = offA[s] + rkAab[i]; if (pA > 2 * E_AB - 1) pA = 2 * E_AB - 1;
        int pB = offB[d] + rkBab[i]; if (pB > E_AB - 1) pB = E_AB - 1;
        idxA[pA] = enc_entry(d, 1, sraw);   // flag 1: AB edge, src in x_b
        idxB[pB] = enc_entry(s, 0, sraw);   // flag 0 (all AB for TB)
    }
    if (i < E_AA) {
        const float sraw = scAA[i];
        scAA[i] = __expf(sraw - Maa) * rLaa;
        const int s = ei_aa[i];
        const int daa = ei_aa[E_AA + i];
        int pA = offA[s] + rkAaa[i]; if (pA > 2 * E_AB - 1) pA = 2 * E_AB - 1;
        idxA[pA] = enc_entry(daa, 0, sraw); // flag 0: AA edge, src in x_a
    }
}

// ---------------------------------------------------------------------------
// Merged gather+final for BOTH node types in one grid:
//  blocks [0,nblkA) -> TA (flag0=AA: src xa16, ML[2,3]; flag1=AB: xb16, ML[0,1])
//  blocks [nblkA,..) -> TB (flag0=AB: src xa16, ML[0,1])
// Phase 2: final MFMA (T <- T + T@FT + fb) on the same 16 rows (L2-hot).
// ---------------------------------------------------------------------------
__global__ __launch_bounds__(256) void gather_all(
    const int* __restrict__ offA, const uint_t* __restrict__ idxA,
    const int* __restrict__ offB, const uint_t* __restrict__ idxB,
    const ushort_t* __restrict__ xa16, const ushort_t* __restrict__ xb16,
    const float* __restrict__ ML,
    const float* __restrict__ x_a, const float* __restrict__ x_b,
    const ushort_t* __restrict__ Bh, const ushort_t* __restrict__ Bl,
    const float* __restrict__ fb,
    float* __restrict__ TA, float* __restrict__ TB, int nblkA)
{
    const int lane = threadIdx.x & 63;
    const int l15  = lane & 15, lg = lane >> 4;
    const int wv   = threadIdx.x >> 6;
    const int isA  = (blockIdx.x < nblkA);
    const int bb   = isA ? blockIdx.x : (blockIdx.x - nblkA);
    const int r0   = bb * 64 + wv * 16;
    const int N    = isA ? N_A : N_B;

    const int*    __restrict__ off = isA ? offA : offB;
    const uint_t* __restrict__ idx = isA ? idxA : idxB;
    const float*  __restrict__ xself = isA ? x_a : x_b;
    float* __restrict__ T = isA ? TA : TB;

    // flag0: A-half -> AA stats (ML[2,3]); B-half -> AB stats (ML[0,1]).
    // flag1 (A-half only): AB stats. Source arrays identical in both halves.
    const float M0  = isA ? ML[2] : ML[0];
    const float rL0 = 1.0f / (isA ? ML[3] : ML[1]);
    const float M1  = ML[0];
    const float rL1 = 1.0f / ML[1];

    for (int s = 0; s < 4; ++s) {
        const int row = r0 + s * 4 + lg;
        if (row < N) {
            const int beg = off[row], end = off[row + 1];
            float a8[8];
            *(float4*)(a8 + 0) = *(const float4*)&xself[(size_t)row * 128 + l15 * 8];
            *(float4*)(a8 + 4) = *(const float4*)&xself[(size_t)row * 128 + l15 * 8 + 4];
            int e = beg;
            for (; e + 3 < end; e += 4) {
                uint_t v[4];
#pragma unroll
                for (int k = 0; k < 4; ++k) v[k] = idx[e + k];
                uint4 f[4];
#pragma unroll
                for (int k = 0; k < 4; ++k) {
                    const ushort_t* sp = (v[k] & 0x10000u) ? xb16 : xa16;
                    f[k] = *(const uint4*)&sp[(size_t)(v[k] & 0xFFFFu) * 128 + l15 * 8];
                }
#pragma unroll
                for (int k = 0; k < 4; ++k) {
                    const int fl = (v[k] >> 16) & 1;
                    const float sc = f16f((ushort_t)((v[k] >> 16) & 0xFFFEu));
                    const float al = __expf(sc - (fl ? M1 : M0)) * (fl ? rL1 : rL0);
                    const __half2* hp = (const __half2*)&f[k];
#pragma unroll
                    for (int j = 0; j < 4; ++j) {
                        const float2 vf = __half22float2(hp[j]);
                        a8[2 * j]     = fmaf(-al, vf.x, a8[2 * j]);
                        a8[2 * j + 1] = fmaf(-al, vf.y, a8[2 * j + 1]);
                    }
                }
            }
            for (; e < end; ++e) {
                const uint_t v = idx[e];
                const ushort_t* sp = (v & 0x10000u) ? xb16 : xa16;
                const uint4 f0 = *(const uint4*)&sp[(size_t)(v & 0xFFFFu) * 128 + l15 * 8];
                const int fl = (v >> 16) & 1;
                const float sc = f16f((ushort_t)((v >> 16) & 0xFFFEu));
                const float al = __expf(sc - (fl ? M1 : M0)) * (fl ? rL1 : rL0);
                const __half2* hp = (const __half2*)&f0;
#pragma unroll
                for (int j = 0; j < 4; ++j) {
                    const float2 vf = __half22float2(hp[j]);
                    a8[2 * j]     = fmaf(-al, vf.x, a8[2 * j]);
                    a8[2 * j + 1] = fmaf(-al, vf.y, a8[2 * j + 1]);
                }
            }
            *(float4*)&T[(size_t)row * 128 + l15 * 8]     = *(float4*)(a8 + 0);
            *(float4*)&T[(size_t)row * 128 + l15 * 8 + 4] = *(float4*)(a8 + 4);
        }
    }
    __syncthreads();

    const int arow = (r0 + l15 < N) ? (r0 + l15) : (N - 1);
    bf16x8 ahi[4], alo[4];
#pragma unroll
    for (int kt = 0; kt < 4; ++kt) {
        float v[8];
        *(float4*)(v + 0) = *(const float4*)&T[(size_t)arow * 128 + kt * 32 + lg * 8];
        *(float4*)(v + 4) = *(const float4*)&T[(size_t)arow * 128 + kt * 32 + lg * 8 + 4];
#pragma unroll
        for (int j = 0; j < 8; ++j) {
            const ushort_t h = bf16r(v[j]);
            ahi[kt][j] = (short)h;
            alo[kt][j] = (short)bf16r(v[j] - bf2f(h));
        }
    }

    f32x4 acc[8];
#pragma unroll
    for (int ct = 0; ct < 8; ++ct) {
        const float b = fb[ct * 16 + l15];
#pragma unroll
        for (int i = 0; i < 4; ++i) {
            const int row = r0 + lg * 4 + i;
            const int rr = (row < N) ? row : (N - 1);
            acc[ct][i] = T[(size_t)rr * 128 + ct * 16 + l15] + b;
        }
    }

#pragma unroll
    for (int ct = 0; ct < 8; ++ct) {
#pragma unroll
        for (int kt = 0; kt < 4; ++kt) {
            const size_t fo = (size_t)((ct * 4 + kt) * 64 + lane) * 8;
            const bf16x8 bhf = *(const bf16x8*)&Bh[fo];
            const bf16x8 blf = *(const bf16x8*)&Bl[fo];
            acc[ct] = __builtin_amdgcn_mfma_f32_16x16x32_bf16(ahi[kt], bhf, acc[ct], 0, 0, 0);
            acc[ct] = __builtin_amdgcn_mfma_f32_16x16x32_bf16(alo[kt], bhf, acc[ct], 0, 0, 0);
            acc[ct] = __builtin_amdgcn_mfma_f32_16x16x32_bf16(ahi[kt], blf, acc[ct], 0, 0, 0);
        }
    }
#pragma unroll
    for (int ct = 0; ct < 8; ++ct) {
#pragma unroll
        for (int i = 0; i < 4; ++i) {
            const int row = r0 + lg * 4 + i;
            if (row < N) T[(size_t)row * 128 + ct * 16 + l15] = acc[ct][i];
        }
    }
}

// ---------------------------------------------------------------------------
extern "C" void kernel_launch(void* const* d_in, const int* in_sizes, int n_in,
                              void* d_out, int out_size, void* d_ws, size_t ws_size,
                              hipStream_t stream)
{
    const float* x_a   = (const float*)d_in[0];
    const float* x_b   = (const float*)d_in[1];
    const int*   ei_ab = (const int*)d_in[2];
    const float* ea_ab = (const float*)d_in[3];
    const int*   ei_aa = (const int*)d_in[4];
    const float* ea_aa = (const float*)d_in[5];
    const float* Wh_w  = (const float*)d_in[6];
    const float* Wh_b  = (const float*)d_in[7];
    const float* Wn_w  = (const float*)d_in[8];
    const float* Wn_b  = (const float*)d_in[9];
    const float* w_e   = (const float*)d_in[10];
    const float* ft_w  = (const float*)d_in[11];
    const float* ft_b  = (const float*)d_in[12];

    float* out = (float*)d_out;
    float* ws  = (float*)d_ws;

    // ws layout (float offsets; all regions disjoint)
    ushort_t* P1h  = (ushort_t*)(ws);              // 6.4M ushorts
    ushort_t* P2ah = (ushort_t*)(ws + 3200000);
    ushort_t* P2bh = (ushort_t*)(ws + 6400000);
    ushort_t* xa16 = (ushort_t*)(ws + 9600000);
    ushort_t* xb16 = (ushort_t*)(ws + 12800000);
    int* rkAab = (int*)(ws + 16000000);
    int* rkBab = (int*)(ws + 16320000);
    int* rkAaa = (int*)(ws + 16640000);
    int* cntA  = (int*)(ws + 16960000);            // cntA+cntB contiguous
    int* cntB  = (int*)(ws + 17010000);
    int* offA  = (int*)(ws + 17060000);            // 50001
    int* offB  = (int*)(ws + 17110004);            // 50001
    float* pm  = ws + 17160008;                    // 5000 (2500 per type)
    float* pl  = ws + 17165008;                    // 5000
    float* ML  = ws + 17170008;                    // 4
    float* wep = ws + 17170016;                    // 128
    ushort_t* FR = (ushort_t*)(ws + 17170208);     // 114688 ushorts
    ushort_t* BhWh = FR;
    ushort_t* BlWh = FR + 8192;
    ushort_t* BhW1 = FR + 16384;
    ushort_t* BlW1 = FR + 32768;
    ushort_t* BhW2 = FR + 49152;
    ushort_t* BlW2 = FR + 65536;
    ushort_t* BhFT = FR + 81920;
    ushort_t* BlFT = FR + 98304;                   // ends ws+17227552
    uint_t* idxA = (uint_t*)(ws + 17230000);       // 640000 uints
    uint_t* idxB = (uint_t*)(ws + 17870000);       // 320000 uints -> 18190000

    // d_out layout: out_a[6.4M] out_b[6.4M] alpha_ab[320K] alpha_aa[320K]
    float* TA   = out;
    float* TB   = out + 6400000;
    float* alAB = out + 12800000;   // raw scores, then normalized in csr_fill
    float* alAA = out + 13120000;

    const int nblkA = (N_A + 63) / 64;   // 782
    const int nblkB = (N_B + 63) / 64;   // 782

    // 0) zero CSR counters; pack weights
    hipMemsetAsync(cntA, 0, 100000 * sizeof(int), stream);
    prep_w_all<<<113, 64, 0, stream>>>(Wh_w, Wn_w, Wn_w + 128 * 128, ft_w, w_e,
                                       BhWh, BlWh, BhW1, BlW1, BhW2, BlW2, BhFT, BlFT, wep);

    // 1) merged node projections (A dual + B single in one grid)
    proj_all_mfma<<<nblkA + nblkB, 256, 0, stream>>>(x_a, x_b,
                                                     BhW1, BlW1, BhW2, BlW2,
                                                     Wh_b, Wn_b,
                                                     P1h, P2ah, P2bh, xa16, xb16, nblkA);

    // 2) merged edge scores (round-9 body)
    edge_score_k<<<5000, 512, 0, stream>>>(ea_ab, ea_aa, ei_ab, ei_aa,
                                           P1h, P2ah, P2bh, BhWh, BlWh, wep,
                                           alAB, alAA, cntA, cntB,
                                           rkAab, rkBab, rkAaa, pm, pl);

    // 3) merged softmax-final + CSR-scan (4 independent blocks)
    softmax_scan_kernel<<<4, 1024, 0, stream>>>(pm, pl, ML, 2500,
                                                cntA, offA, cntB, offB, N_A);

    // 4) atomic-free fill (4B entries, fused normalization)
    csr_fill_kernel<<<(E_AB + 255) / 256, 256, 0, stream>>>(ei_ab, ei_aa, alAB, alAA, ML,
                                                            offA, offB, rkAab, rkBab, rkAaa,
                                                            idxA, idxB);

    // 5) merged gather + final transform (A and B in one grid)
    gather_all<<<nblkA + nblkB, 256, 0, stream>>>(offA, idxA, offB, idxB,
                                                  xa16, xb16, ML, x_a, x_b,
                                                  BhFT, BlFT, ft_b, TA, TB, nblkA);

    (void)in_sizes; (void)n_in; (void)out_size; (void)ws_size;
}